// Round 10
// baseline (982.459 us; speedup 1.0000x reference)
//
#include <hip/hip_runtime.h>

#define EPSV 1e-5f
#define NEGINF -3.402823466e38f
#define NBMAX 1600
#define CHUNK 8192
#define CAP3 6144

typedef short bf16x8 __attribute__((ext_vector_type(8)));
typedef float f32x4 __attribute__((ext_vector_type(4)));

__device__ __forceinline__ unsigned short f2bf(float f) {
    union { float f; unsigned i; } c; c.f = f;
    unsigned r = c.i + 0x7fff + ((c.i >> 16) & 1);
    return (unsigned short)(r >> 16);
}
__device__ __forceinline__ float blo(unsigned u) {
    union { unsigned i; float f; } c; c.i = u << 16; return c.f;
}
__device__ __forceinline__ float bhi(unsigned u) {
    union { unsigned i; float f; } c; c.i = u & 0xffff0000u; return c.f;
}
__device__ __forceinline__ float bfu(unsigned short u) {
    union { unsigned i; float f; } c; c.i = ((unsigned)u) << 16; return c.f;
}

// ---------------------------------------------------------------- lin1 + stats
__global__ __launch_bounds__(256)
void k_lin1(const float* __restrict__ x, const float* __restrict__ w,
            const float* __restrict__ bvec, unsigned short* __restrict__ outb,
            float* __restrict__ stats, int N)
{
    __shared__ float wl[27 * 128];
    int tid = threadIdx.x;
    for (int i = tid; i < 27 * 128; i += 256) wl[i] = w[i];
    __syncthreads();

    int l  = tid & 63;
    int wv = tid >> 6;
    float bv0 = bvec[l], bv1 = bvec[64 + l];
    int waveSlots = gridDim.x * 4;
    int trips = (N + waveSlots - 1) / waveSlots;
    float s0 = 0.f, q0 = 0.f, s1 = 0.f, q1 = 0.f;
    for (int it = 0; it < trips; ++it) {
        int n = (it * gridDim.x + blockIdx.x) * 4 + wv;
        if (n < N) {
            const float* xr = x + (size_t)n * 27;
            float a0 = bv0, a1 = bv1;
            #pragma unroll
            for (int k = 0; k < 27; ++k) {
                float xv = xr[k];
                a0 = fmaf(xv, wl[k * 128 + l], a0);
                a1 = fmaf(xv, wl[k * 128 + 64 + l], a1);
            }
            outb[(size_t)n * 128 + l] = f2bf(a0);
            outb[(size_t)n * 128 + 64 + l] = f2bf(a1);
            s0 += a0; q0 += a0 * a0; s1 += a1; q1 += a1 * a1;
        }
    }
    __shared__ float sred[4][256];
    sred[0][tid] = s0; sred[1][tid] = q0;
    sred[2][tid] = s1; sred[3][tid] = q1;
    __syncthreads();
    if (tid < 64) {
        int t = tid;
        float v0 = sred[0][t] + sred[0][t + 64] + sred[0][t + 128] + sred[0][t + 192];
        float v1 = sred[1][t] + sred[1][t + 64] + sred[1][t + 128] + sred[1][t + 192];
        float v2 = sred[2][t] + sred[2][t + 64] + sred[2][t + 128] + sred[2][t + 192];
        float v3 = sred[3][t] + sred[3][t + 64] + sred[3][t + 128] + sred[3][t + 192];
        atomicAdd(stats + t, v0);
        atomicAdd(stats + 128 + t, v1);
        atomicAdd(stats + 64 + t, v2);
        atomicAdd(stats + 192 + t, v3);
    }
}

// ---------------------------------------------------------------- prep: hist + scan (last block) + gbound
__global__ __launch_bounds__(256)
void k_prep(const int* __restrict__ dst, int* __restrict__ bcnt, int* __restrict__ bbase,
            int E, int NB, int shift, const int* __restrict__ batch,
            int* __restrict__ gstart, int N, int G, int* __restrict__ arrive)
{
    const int HB = 256;
    int tid = threadIdx.x;
    __shared__ int hist[NBMAX];
    __shared__ int buf2[NBMAX];
    __shared__ int partl[256];
    __shared__ int lastf;

    if (blockIdx.x < HB) {
        for (int i = tid; i < NB; i += 256) hist[i] = 0;
        __syncthreads();
        int stride = HB * 256;
        for (int e = blockIdx.x * 256 + tid; e < E; e += stride)
            atomicAdd(&hist[dst[e] >> shift], 1);
        __syncthreads();
        for (int i = tid; i < NB; i += 256)
            if (hist[i]) atomicAdd(bcnt + i, hist[i]);
        __syncthreads();
        if (tid == 0) {
            __threadfence();
            int tk = atomicAdd(arrive, 1);
            lastf = (tk == HB - 1) ? 1 : 0;
        }
        __syncthreads();
        if (lastf) {
            __threadfence();
            int per = (NB + 255) / 256;
            int beg = tid * per, end = min(beg + per, NB);
            int s = 0;
            for (int i = beg; i < end; ++i) { int v = bcnt[i]; buf2[i] = s; s += v; }
            partl[tid] = s;
            __syncthreads();
            for (int ofs = 1; ofs < 256; ofs <<= 1) {
                int u = (tid >= ofs) ? partl[tid - ofs] : 0;
                __syncthreads();
                partl[tid] += u;
                __syncthreads();
            }
            int add = partl[tid] - s;
            for (int i = beg; i < end; ++i) bbase[i] = buf2[i] + add;
            if (tid == 0) bbase[NB] = E;
        }
    } else {
        int b = blockIdx.x - HB;
        int stride = (gridDim.x - HB) * 256;
        for (int n = b * 256 + tid; n < N; n += stride) {
            int bb = batch[n];
            if (n == 0) {
                for (int g = 0; g <= bb; ++g) gstart[g] = 0;
            } else {
                int pb = batch[n - 1];
                for (int g = pb + 1; g <= bb; ++g) gstart[g] = n;
            }
            if (n == N - 1) {
                for (int g = bb + 1; g <= G; ++g) gstart[g] = N;
            }
        }
    }
}

// ---------------------------------------------------------------- bucketed scatter
__global__ __launch_bounds__(256)
void k_p2_scatter(const int* __restrict__ src, const int* __restrict__ dst,
                  const int* __restrict__ bbase, int* __restrict__ bcur0,
                  uint2* __restrict__ bucketed, int E, int NB, int shift)
{
    __shared__ uint2 ebuf[CHUNK];
    __shared__ int hist[NBMAX];
    __shared__ int cur[NBMAX];
    __shared__ int wtmp[256];
    int tid = threadIdx.x;
    int c0 = blockIdx.x * CHUNK;
    int cc = min(CHUNK, E - c0);
    if (cc <= 0) return;

    for (int i = tid; i < NB; i += 256) hist[i] = 0;
    __syncthreads();
    for (int i = tid; i < cc; i += 256)
        atomicAdd(&hist[dst[c0 + i] >> shift], 1);
    __syncthreads();
    int per = (NB + 255) / 256;
    int beg = tid * per, end = min(beg + per, NB);
    int s = 0;
    for (int i = beg; i < end; ++i) s += hist[i];
    wtmp[tid] = s;
    __syncthreads();
    for (int ofs = 1; ofs < 256; ofs <<= 1) {
        int u = (tid >= ofs) ? wtmp[tid - ofs] : 0;
        __syncthreads();
        wtmp[tid] += u;
        __syncthreads();
    }
    int run = wtmp[tid] - s;
    for (int i = beg; i < end; ++i) { cur[i] = run; run += hist[i]; }
    __syncthreads();
    for (int i = tid; i < cc; i += 256) {
        int sv = src[c0 + i], dv = dst[c0 + i];
        int b = dv >> shift;
        int pos = atomicAdd(&cur[b], 1);
        ebuf[pos] = make_uint2((unsigned)sv, (unsigned)dv);
    }
    __syncthreads();
    for (int b = tid; b < NB; b += 256) {
        int c = hist[b];
        if (c > 0) {
            int lb = cur[b] - c;
            int gb = bbase[b] + atomicAdd(&bcur0[b], c);
            hist[b] = gb - lb;
        }
    }
    __syncthreads();
    for (int i = tid; i < cc; i += 256) {
        uint2 u = ebuf[i];
        int b = (int)(u.y >> shift);
        bucketed[hist[b] + i] = u;
    }
}

__global__ __launch_bounds__(256)
void k_p3_csr(const uint2* __restrict__ bucketed, const int* __restrict__ bbase,
              int* __restrict__ rowptr, int* __restrict__ csr,
              int N, int NB, int shift)
{
    __shared__ int ncnt[128], nsc[128];
    __shared__ int lcsr[CAP3];
    int b = blockIdx.x;
    int tid = threadIdx.x;
    int e0 = bbase[b], e1 = bbase[b + 1];
    int cnt = e1 - e0;
    int node0 = b << shift;
    int nodes = min(1 << shift, N - node0);

    if (tid < 128) ncnt[tid] = 0;
    __syncthreads();
    for (int i = tid; i < cnt; i += 256)
        atomicAdd(&ncnt[(int)bucketed[e0 + i].y - node0], 1);
    __syncthreads();
    if (tid < 128) nsc[tid] = ncnt[tid];
    __syncthreads();
    for (int ofs = 1; ofs < 128; ofs <<= 1) {
        int u = 0;
        if (tid < 128 && tid >= ofs) u = nsc[tid - ofs];
        __syncthreads();
        if (tid < 128) nsc[tid] += u;
        __syncthreads();
    }
    if (tid < nodes) rowptr[node0 + tid] = e0 + nsc[tid] - ncnt[tid];
    if (tid == 0 && b == NB - 1) rowptr[N] = e1;
    if (tid < 128) ncnt[tid] = nsc[tid] - ncnt[tid];
    __syncthreads();
    if (cnt <= CAP3) {
        for (int i = tid; i < cnt; i += 256) {
            uint2 u = bucketed[e0 + i];
            int d = (int)u.y - node0;
            int pos = atomicAdd(&ncnt[d], 1);
            lcsr[pos] = (int)u.x;
        }
        __syncthreads();
        for (int i = tid; i < cnt; i += 256) csr[e0 + i] = lcsr[i];
    } else {
        for (int i = tid; i < cnt; i += 256) {
            uint2 u = bucketed[e0 + i];
            int d = (int)u.y - node0;
            int pos = atomicAdd(&ncnt[d], 1);
            csr[e0 + pos] = (int)u.x;
        }
    }
}

// ---------------------------------------------------------------- fused BN + MFMA GEMM
__global__ __launch_bounds__(256)
void k_gemm_mfma(const unsigned short* __restrict__ tin, unsigned short* __restrict__ h,
                 const float* __restrict__ stats, const float* __restrict__ gamma,
                 const float* __restrict__ beta, float invN, int residual,
                 const float* __restrict__ basesW, const float* __restrict__ combW,
                 const float* __restrict__ combB,
                 unsigned short* __restrict__ basesP,
                 unsigned short* __restrict__ combB16, int N)
{
    __shared__ unsigned short Wlds[2560 * 8];   // 40 KB
    __shared__ float scL[128], shL[128];
    int tid = threadIdx.x;
    if (tid < 128) {
        float mu  = stats[tid] * invN;
        float var = stats[128 + tid] * invN - mu * mu;
        float sc  = gamma[tid] * rsqrtf(var + EPSV);
        scL[tid] = sc;
        shL[tid] = beta[tid] - mu * sc;
    }
    for (int i = tid; i < 2560; i += 256) {
        int ct = i >> 8, rem = i & 255;
        int ln = rem & 63;
        int n16 = ln & 15, quad = ln >> 4;
        int k = ((rem >> 6) << 5) + quad * 8;
        unsigned short tmp[8];
        if (ct < 4) {
            int c = ct * 16 + n16;
            #pragma unroll
            for (int j = 0; j < 8; ++j) tmp[j] = f2bf(basesW[(k + j) * 64 + c]);
        } else {
            int c = (ct - 4) * 16 + n16;
            #pragma unroll
            for (int j = 0; j < 8; ++j) tmp[j] = f2bf(combW[(k + j) * 96 + c]);
        }
        uint4 pk;
        pk.x = (unsigned)tmp[0] | ((unsigned)tmp[1] << 16);
        pk.y = (unsigned)tmp[2] | ((unsigned)tmp[3] << 16);
        pk.z = (unsigned)tmp[4] | ((unsigned)tmp[5] << 16);
        pk.w = (unsigned)tmp[6] | ((unsigned)tmp[7] << 16);
        *(uint4*)&Wlds[(size_t)i * 8] = pk;
    }
    __syncthreads();

    int lane = tid & 63, wv = tid >> 6;
    int f = lane & 15, quad = lane >> 4;
    float cbv[6];
    #pragma unroll
    for (int s = 0; s < 6; ++s) cbv[s] = combB[s * 16 + f];

    int tiles = (N + 15) >> 4;
    int waveSlots = gridDim.x * 4;
    for (int tile = blockIdx.x * 4 + wv; tile < tiles; tile += waveSlots) {
        int tb = tile * 16;
        int mnode = min(tb + f, N - 1);
        size_t rbase = (size_t)mnode * 128;

        f32x4 acc[10];
        #pragma unroll
        for (int ct = 0; ct < 10; ++ct) acc[ct] = (f32x4){0.f, 0.f, 0.f, 0.f};

        #pragma unroll
        for (int ki = 0; ki < 4; ++ki) {
            int kc = quad * 8 + ki * 32;
            uint4 tv = *(const uint4*)&tin[rbase + kc];
            float r0, r1, r2, r3, r4, r5, r6, r7;
            r0 = fmaxf(blo(tv.x) * scL[kc]     + shL[kc],     0.f);
            r1 = fmaxf(bhi(tv.x) * scL[kc + 1] + shL[kc + 1], 0.f);
            r2 = fmaxf(blo(tv.y) * scL[kc + 2] + shL[kc + 2], 0.f);
            r3 = fmaxf(bhi(tv.y) * scL[kc + 3] + shL[kc + 3], 0.f);
            r4 = fmaxf(blo(tv.z) * scL[kc + 4] + shL[kc + 4], 0.f);
            r5 = fmaxf(bhi(tv.z) * scL[kc + 5] + shL[kc + 5], 0.f);
            r6 = fmaxf(blo(tv.w) * scL[kc + 6] + shL[kc + 6], 0.f);
            r7 = fmaxf(bhi(tv.w) * scL[kc + 7] + shL[kc + 7], 0.f);
            if (residual) {
                uint4 hv = *(const uint4*)&h[rbase + kc];
                r0 += blo(hv.x); r1 += bhi(hv.x); r2 += blo(hv.y); r3 += bhi(hv.y);
                r4 += blo(hv.z); r5 += bhi(hv.z); r6 += blo(hv.w); r7 += bhi(hv.w);
            }
            unsigned short b0 = f2bf(r0), b1 = f2bf(r1), b2 = f2bf(r2), b3 = f2bf(r3);
            unsigned short b4 = f2bf(r4), b5 = f2bf(r5), b6 = f2bf(r6), b7 = f2bf(r7);
            uint4 hw;
            hw.x = (unsigned)b0 | ((unsigned)b1 << 16);
            hw.y = (unsigned)b2 | ((unsigned)b3 << 16);
            hw.z = (unsigned)b4 | ((unsigned)b5 << 16);
            hw.w = (unsigned)b6 | ((unsigned)b7 << 16);
            *(uint4*)&h[rbase + kc] = hw;
            short ab[8] = {(short)b0, (short)b1, (short)b2, (short)b3,
                           (short)b4, (short)b5, (short)b6, (short)b7};
            bf16x8 a = *(bf16x8*)ab;
            #pragma unroll
            for (int ct = 0; ct < 10; ++ct) {
                bf16x8 bfr = *(const bf16x8*)&Wlds[(size_t)((ct * 4 + ki) * 64 + lane) * 8];
                acc[ct] = __builtin_amdgcn_mfma_f32_16x16x32_bf16(a, bfr, acc[ct], 0, 0, 0);
            }
        }

        #pragma unroll
        for (int r = 0; r < 4; ++r) {
            int node = tb + quad * 4 + r;
            if (node < N) {
                #pragma unroll
                for (int ct = 0; ct < 4; ++ct)
                    basesP[(size_t)node * 64 + f * 4 + ct] = f2bf(acc[ct][r]);
                #pragma unroll
                for (int s = 0; s < 6; ++s)
                    combB16[(size_t)node * 96 + s * 16 + f] = f2bf(acc[4 + s][r] + cbv[s]);
            }
        }
    }
}

// ---------------------------------------------------------------- aggregation (two nodes/wave)
__global__ __launch_bounds__(256)
void k_agg(const unsigned short* __restrict__ basesP, const unsigned short* __restrict__ combB16,
           const int* __restrict__ csr, const int* __restrict__ rowptr,
           const float* __restrict__ cbias, unsigned short* __restrict__ outb,
           float* __restrict__ stats, int N)
{
    int l = threadIdx.x & 63;
    int w = threadIdx.x >> 6;
    int f = l & 15, sub = l >> 4;
    const char* bp = (const char*)basesP;
    unsigned fof = (unsigned)(f << 3);
    float cb0 = cbias[l], cb1 = cbias[64 + l];
    int waveSlots = gridDim.x * 4;
    int pairs = (N + 1) >> 1;
    int trips = (pairs + waveSlots - 1) / waveSlots;
    float s0 = 0.f, q0 = 0.f, s1 = 0.f, q1 = 0.f;

    for (int it = 0; it < trips; ++it) {
        int pr = (it * gridDim.x + blockIdx.x) * 4 + w;
        if (pr < pairs) {
            int nA = pr * 2;
            bool hasB = (nA + 1) < N;
            int nB = hasB ? nA + 1 : nA;
            int rA = rowptr[nA];
            int cA = rowptr[nA + 1] - rA;
            int rB = rowptr[nB];
            int cB = hasB ? (rowptr[nB + 1] - rB) : 0;

            float SA0 = 0.f, SA1 = 0.f, SA2 = 0.f, SA3 = 0.f;
            float MA0 = NEGINF, MA1 = NEGINF, MA2 = NEGINF, MA3 = NEGINF;
            float SB0 = 0.f, SB1 = 0.f, SB2 = 0.f, SB3 = 0.f;
            float MB0 = NEGINF, MB1 = NEGINF, MB2 = NEGINF, MB3 = NEGINF;

            int mt = (max(cA, cB) + 3) >> 2;
            int e = sub;
            #pragma unroll 2
            for (int t = 0; t < mt; ++t) {
                int eA = max(min(e, cA - 1), 0);
                int eB = max(min(e, cB - 1), 0);
                int snA = csr[rA + eA];
                int snB = csr[rB + eB];
                uint2 uA = *(const uint2*)(bp + (((unsigned)snA) << 7) + fof);
                uint2 uB = *(const uint2*)(bp + (((unsigned)snB) << 7) + fof);
                bool vA = e < cA, vB = e < cB;
                float a0 = blo(uA.x), a1 = bhi(uA.x), a2 = blo(uA.y), a3 = bhi(uA.y);
                float b0 = blo(uB.x), b1 = bhi(uB.x), b2 = blo(uB.y), b3 = bhi(uB.y);
                SA0 += vA ? a0 : 0.f; SA1 += vA ? a1 : 0.f;
                SA2 += vA ? a2 : 0.f; SA3 += vA ? a3 : 0.f;
                MA0 = fmaxf(MA0, vA ? a0 : NEGINF); MA1 = fmaxf(MA1, vA ? a1 : NEGINF);
                MA2 = fmaxf(MA2, vA ? a2 : NEGINF); MA3 = fmaxf(MA3, vA ? a3 : NEGINF);
                SB0 += vB ? b0 : 0.f; SB1 += vB ? b1 : 0.f;
                SB2 += vB ? b2 : 0.f; SB3 += vB ? b3 : 0.f;
                MB0 = fmaxf(MB0, vB ? b0 : NEGINF); MB1 = fmaxf(MB1, vB ? b1 : NEGINF);
                MB2 = fmaxf(MB2, vB ? b2 : NEGINF); MB3 = fmaxf(MB3, vB ? b3 : NEGINF);
                e += 4;
            }

            #pragma unroll
            for (int m = 0; m < 2; ++m) {
                if (m == 1 && !hasB) break;
                int n = (m == 0) ? nA : nB;
                int cnt = (m == 0) ? cA : cB;
                float T0 = (m == 0) ? SA0 : SB0, T1 = (m == 0) ? SA1 : SB1;
                float T2 = (m == 0) ? SA2 : SB2, T3 = (m == 0) ? SA3 : SB3;
                float X0 = (m == 0) ? MA0 : MB0, X1 = (m == 0) ? MA1 : MB1;
                float X2 = (m == 0) ? MA2 : MB2, X3 = (m == 0) ? MA3 : MB3;
                T0 += __shfl_xor(T0, 16, 64); T1 += __shfl_xor(T1, 16, 64);
                T2 += __shfl_xor(T2, 16, 64); T3 += __shfl_xor(T3, 16, 64);
                T0 += __shfl_xor(T0, 32, 64); T1 += __shfl_xor(T1, 32, 64);
                T2 += __shfl_xor(T2, 32, 64); T3 += __shfl_xor(T3, 32, 64);
                X0 = fmaxf(X0, __shfl_xor(X0, 16, 64)); X1 = fmaxf(X1, __shfl_xor(X1, 16, 64));
                X2 = fmaxf(X2, __shfl_xor(X2, 16, 64)); X3 = fmaxf(X3, __shfl_xor(X3, 16, 64));
                X0 = fmaxf(X0, __shfl_xor(X0, 32, 64)); X1 = fmaxf(X1, __shfl_xor(X1, 32, 64));
                X2 = fmaxf(X2, __shfl_xor(X2, 32, 64)); X3 = fmaxf(X3, __shfl_xor(X3, 32, 64));
                uint2 su = *(const uint2*)(bp + (((unsigned)n) << 7) + fof);
                float w0 = blo(su.x), w1 = bhi(su.x), w2 = blo(su.y), w3 = bhi(su.y);
                T0 += w0; T1 += w1; T2 += w2; T3 += w3;
                X0 = fmaxf(X0, w0); X1 = fmaxf(X1, w1);
                X2 = fmaxf(X2, w2); X3 = fmaxf(X3, w3);
                float invd = 1.f / (float)(cnt + 1);
                float A0 = T0 * invd, A1 = T1 * invd, A2 = T2 * invd, A3 = T3 * invd;

                const unsigned short* cr = combB16 + (size_t)n * 96;
                const uint2* c0p = (const uint2*)(cr + sub * 12);
                const uint2* c1p = (const uint2*)(cr + 48 + sub * 12);
                uint2 qa0 = c0p[0], qa1 = c0p[1], qa2 = c0p[2];
                uint2 qb0 = c1p[0], qb1 = c1p[1], qb2 = c1p[2];

                float o0 = cb0, o1 = cb1;
                o0 = fmaf(blo(qa0.x), T0, o0); o0 = fmaf(bhi(qa0.x), T1, o0);
                o0 = fmaf(blo(qa0.y), T2, o0); o0 = fmaf(bhi(qa0.y), T3, o0);
                o0 = fmaf(blo(qa1.x), A0, o0); o0 = fmaf(bhi(qa1.x), A1, o0);
                o0 = fmaf(blo(qa1.y), A2, o0); o0 = fmaf(bhi(qa1.y), A3, o0);
                o0 = fmaf(blo(qa2.x), X0, o0); o0 = fmaf(bhi(qa2.x), X1, o0);
                o0 = fmaf(blo(qa2.y), X2, o0); o0 = fmaf(bhi(qa2.y), X3, o0);
                o1 = fmaf(blo(qb0.x), T0, o1); o1 = fmaf(bhi(qb0.x), T1, o1);
                o1 = fmaf(blo(qb0.y), T2, o1); o1 = fmaf(bhi(qb0.y), T3, o1);
                o1 = fmaf(blo(qb1.x), A0, o1); o1 = fmaf(bhi(qb1.x), A1, o1);
                o1 = fmaf(blo(qb1.y), A2, o1); o1 = fmaf(bhi(qb1.y), A3, o1);
                o1 = fmaf(blo(qb2.x), X0, o1); o1 = fmaf(bhi(qb2.x), X1, o1);
                o1 = fmaf(blo(qb2.y), X2, o1); o1 = fmaf(bhi(qb2.y), X3, o1);

                outb[(size_t)n * 128 + l] = f2bf(o0);
                outb[(size_t)n * 128 + 64 + l] = f2bf(o1);
                s0 += o0; q0 += o0 * o0; s1 += o1; q1 += o1 * o1;
            }
        }
    }
    __shared__ float sred[4][256];
    sred[0][threadIdx.x] = s0; sred[1][threadIdx.x] = q0;
    sred[2][threadIdx.x] = s1; sred[3][threadIdx.x] = q1;
    __syncthreads();
    if (threadIdx.x < 64) {
        int t = threadIdx.x;
        float v0 = sred[0][t] + sred[0][t + 64] + sred[0][t + 128] + sred[0][t + 192];
        float v1 = sred[1][t] + sred[1][t + 64] + sred[1][t + 128] + sred[1][t + 192];
        float v2 = sred[2][t] + sred[2][t + 64] + sred[2][t + 128] + sred[2][t + 192];
        float v3 = sred[3][t] + sred[3][t + 64] + sred[3][t + 128] + sred[3][t + 192];
        atomicAdd(stats + t, v0);
        atomicAdd(stats + 128 + t, v1);
        atomicAdd(stats + 64 + t, v2);
        atomicAdd(stats + 192 + t, v3);
    }
}

// ---------------------------------------------------------------- tail: pool+mlp1 per graph, last block mlp2+mlp3
__global__ __launch_bounds__(256)
void k_tail(const unsigned short* __restrict__ t, const unsigned short* __restrict__ h,
            const float* __restrict__ stats4, const float* __restrict__ gamma,
            const float* __restrict__ beta, float invN, const int* __restrict__ gstart,
            const float* __restrict__ w1, float* __restrict__ t1, float* __restrict__ st5,
            const float* __restrict__ g1, const float* __restrict__ b1,
            const float* __restrict__ w2, float* __restrict__ t2,
            const float* __restrict__ g2, const float* __restrict__ b2,
            const float* __restrict__ w3, const float* __restrict__ b3,
            float* __restrict__ out, float invG, int G, int* __restrict__ arrive)
{
    __shared__ float tg[128];
    __shared__ float part[128];
    __shared__ float red[4][64];
    __shared__ int lastf;
    __shared__ float sc1[64], sh1[64], s6[64];
    __shared__ float sc2[32], sh2[32];

    int g = blockIdx.x;
    int tid = threadIdx.x;
    // ---- pooled row (fused final BN + residual mean)
    {
        int c = tid & 127, half = tid >> 7;
        float mu  = stats4[c] * invN;
        float var = stats4[128 + c] * invN - mu * mu;
        float sc  = gamma[c] * rsqrtf(var + EPSV);
        float sh  = beta[c] - mu * sc;
        int s = gstart[g], e = gstart[g + 1];
        float acc = 0.f;
        #pragma unroll 2
        for (int n = s + half; n < e; n += 2) {
            size_t o = (size_t)n * 128 + c;
            acc += bfu(h[o]) + fmaxf(bfu(t[o]) * sc + sh, 0.f);
        }
        if (half) part[c] = acc;
        __syncthreads();
        if (!half) tg[c] = (acc + part[c]) / fmaxf((float)(e - s), 1.f);
        __syncthreads();
    }
    // ---- mlp1: t1 row + stats
    {
        int cc = tid & 63, pp = tid >> 6;
        float a = 0.f;
        int k0 = pp * 32;
        #pragma unroll
        for (int k = 0; k < 32; ++k)
            a = fmaf(tg[k0 + k], w1[(k0 + k) * 64 + cc], a);
        red[pp][cc] = a;
        __syncthreads();
        if (tid < 64) {
            float v = red[0][tid] + red[1][tid] + red[2][tid] + red[3][tid];
            t1[g * 64 + tid] = v;
            atomicAdd(st5 + tid, v);
            atomicAdd(st5 + 64 + tid, v * v);
        }
    }
    // ---- arrival
    if (tid == 0) {
        __threadfence();
        int tk = atomicAdd(arrive, 1);
        lastf = (tk == G - 1) ? 1 : 0;
    }
    __syncthreads();
    if (!lastf) return;
    __threadfence();
    // ---- last block: mlp2 for all graphs
    if (tid < 64) {
        float m  = st5[tid] * invG;
        float vv = st5[64 + tid] * invG - m * m;
        float s_ = g1[tid] * rsqrtf(vv + EPSV);
        sc1[tid] = s_;
        sh1[tid] = b1[tid] - m * s_;
        s6[tid] = 0.f;
    }
    __syncthreads();
    {
        int cc = tid & 31, gofs = tid >> 5;   // 8 graph-groups
        float sacc = 0.f, qacc = 0.f;
        for (int gg = gofs; gg < G; gg += 8) {
            float a = 0.f;
            #pragma unroll 8
            for (int k = 0; k < 64; ++k) {
                float rv = fmaxf(t1[gg * 64 + k] * sc1[k] + sh1[k], 0.f);
                a = fmaf(rv, w2[k * 32 + cc], a);
            }
            t2[gg * 32 + cc] = a;
            sacc += a; qacc += a * a;
        }
        atomicAdd(&s6[cc], sacc);
        atomicAdd(&s6[32 + cc], qacc);
    }
    __syncthreads();
    if (tid < 32) {
        float m  = s6[tid] * invG;
        float vv = s6[32 + tid] * invG - m * m;
        float s_ = g2[tid] * rsqrtf(vv + EPSV);
        sc2[tid] = s_;
        sh2[tid] = b2[tid] - m * s_;
    }
    __syncthreads();
    // ---- mlp3
    for (int idx = tid; idx < G * 10; idx += 256) {
        int gg = idx / 10, cc = idx - gg * 10;
        float a = b3[cc];
        #pragma unroll 8
        for (int k = 0; k < 32; ++k) {
            float rv = fmaxf(t2[gg * 32 + k] * sc2[k] + sh2[k], 0.f);
            a = fmaf(rv, w3[k * 10 + cc], a);
        }
        out[idx] = a;
    }
}

// ---------------------------------------------------------------- launch
extern "C" void kernel_launch(void* const* d_in, const int* in_sizes, int n_in,
                              void* d_out, int out_size, void* d_ws, size_t ws_size,
                              hipStream_t stream)
{
    const float* x        = (const float*)d_in[0];
    const float* lin1_w   = (const float*)d_in[1];
    const float* lin1_b   = (const float*)d_in[2];
    const float* bn1_g    = (const float*)d_in[3];
    const float* bn1_b    = (const float*)d_in[4];
    const float* bases_w  = (const float*)d_in[5];
    const float* comb_w   = (const float*)d_in[6];
    const float* comb_b   = (const float*)d_in[7];
    const float* conv_bias= (const float*)d_in[8];
    const float* bn_g     = (const float*)d_in[9];
    const float* bn_b     = (const float*)d_in[10];
    const float* mlp_w1   = (const float*)d_in[11];
    const float* mbn1_g   = (const float*)d_in[12];
    const float* mbn1_b   = (const float*)d_in[13];
    const float* mlp_w2   = (const float*)d_in[14];
    const float* mbn2_g   = (const float*)d_in[15];
    const float* mbn2_b   = (const float*)d_in[16];
    const float* mlp_w3   = (const float*)d_in[17];
    const float* mlp_b3   = (const float*)d_in[18];
    const int*   edge_idx = (const int*)d_in[19];
    const int*   batch    = (const int*)d_in[20];
    float* outp = (float*)d_out;

    const int N = in_sizes[20];
    const int E = in_sizes[19] / 2;
    const int G = out_size / 10;
    const int* esrc = edge_idx;
    const int* edst = edge_idx + E;

    int shift = 6;
    while ((((N - 1) >> shift) + 1) > NBMAX && shift < 7) ++shift;
    const int NB = ((N - 1) >> shift) + 1;

    char* p = (char*)d_ws;
    auto alloc = [&](size_t bytes) {
        char* r = p;
        p += (bytes + 255) & ~(size_t)255;
        return r;
    };
    unsigned short* h      = (unsigned short*)alloc((size_t)N * 128 * 2);
    unsigned short* basesP = (unsigned short*)alloc((size_t)N * 64 * 2);
    unsigned short* combB16= (unsigned short*)alloc((size_t)N * 96 * 2);
    unsigned short* outb   = (unsigned short*)alloc((size_t)N * 128 * 2);
    int*            csr    = (int*)  alloc((size_t)(E + 64) * 4);
    int*            rowptr = (int*)  alloc((size_t)(N + 1) * 4);
    int*            bbase  = (int*)  alloc((size_t)(NB + 1) * 4);
    float*          t1     = (float*)alloc((size_t)G * 64 * 4);
    float*          t2     = (float*)alloc((size_t)G * 32 * 4);
    int*            gstart = (int*)  alloc((size_t)(G + 1) * 4);
    char*           zbase  = p;
    int*            bcnt   = (int*)  alloc((size_t)NB * 4);
    int*            bcur0  = (int*)  alloc((size_t)NB * 4);
    float*          stats  = (float*)alloc(7 * 256 * 4);
    int*            arrive = (int*)  alloc(2 * 4);
    size_t zbytes = (size_t)(p - zbase);
    uint2* bucketed = (uint2*)combB16;   // alias: CSR build done before gemm writes
    (void)ws_size; (void)n_in;

    hipMemsetAsync(zbase, 0, zbytes, stream);

    const float invN = 1.0f / (float)N;
    const float invG = 1.0f / (float)G;

    k_lin1<<<1024, 256, 0, stream>>>(x, lin1_w, lin1_b, outb, stats, N);
    k_prep<<<768, 256, 0, stream>>>(edst, bcnt, bbase, E, NB, shift,
                                    batch, gstart, N, G, arrive);
    k_p2_scatter<<<(E + CHUNK - 1) / CHUNK, 256, 0, stream>>>(esrc, edst, bbase, bcur0,
                                                              bucketed, E, NB, shift);
    k_p3_csr<<<NB, 256, 0, stream>>>(bucketed, bbase, rowptr, csr, N, NB, shift);

    for (int l = 0; l < 4; ++l) {
        const float* bw = bases_w + (size_t)l * 128 * 64;
        const float* cw = comb_w + (size_t)l * 128 * 96;
        const float* cb = comb_b + (size_t)l * 96;
        const float* cvb = conv_bias + (size_t)l * 128;
        const float* pg = (l == 0) ? bn1_g : bn_g + (l - 1) * 128;
        const float* pb = (l == 0) ? bn1_b : bn_b + (l - 1) * 128;
        k_gemm_mfma<<<512, 256, 0, stream>>>(outb, h, stats + l * 256, pg, pb, invN,
                                             l > 0 ? 1 : 0, bw, cw, cb, basesP, combB16, N);
        k_agg<<<2048, 256, 0, stream>>>(basesP, combB16, csr, rowptr, cvb,
                                        outb, stats + (1 + l) * 256, N);
    }

    k_tail<<<G, 256, 0, stream>>>(outb, h, stats + 4 * 256, bn_g + 3 * 128,
                                  bn_b + 3 * 128, invN, gstart,
                                  mlp_w1, t1, stats + 5 * 256,
                                  mbn1_g, mbn1_b, mlp_w2, t2,
                                  mbn2_g, mbn2_b, mlp_w3, mlp_b3,
                                  outp, invG, G, arrive + 1);
}

// Round 11
// 816.627 us; speedup vs baseline: 1.2031x; 1.2031x over previous
//
#include <hip/hip_runtime.h>

#define EPSV 1e-5f
#define NEGINF -3.402823466e38f
#define NBMAX 1600
#define CHUNK 8192
#define CAP3 6144

typedef short bf16x8 __attribute__((ext_vector_type(8)));
typedef float f32x4 __attribute__((ext_vector_type(4)));

__device__ __forceinline__ unsigned short f2bf(float f) {
    union { float f; unsigned i; } c; c.f = f;
    unsigned r = c.i + 0x7fff + ((c.i >> 16) & 1);
    return (unsigned short)(r >> 16);
}
__device__ __forceinline__ float blo(unsigned u) {
    union { unsigned i; float f; } c; c.i = u << 16; return c.f;
}
__device__ __forceinline__ float bhi(unsigned u) {
    union { unsigned i; float f; } c; c.i = u & 0xffff0000u; return c.f;
}
__device__ __forceinline__ float bfu(unsigned short u) {
    union { unsigned i; float f; } c; c.i = ((unsigned)u) << 16; return c.f;
}

// ---------------------------------------------------------------- lin1 + stats
__global__ __launch_bounds__(256)
void k_lin1(const float* __restrict__ x, const float* __restrict__ w,
            const float* __restrict__ bvec, unsigned short* __restrict__ outb,
            float* __restrict__ stats, int N)
{
    __shared__ float wl[27 * 128];
    int tid = threadIdx.x;
    for (int i = tid; i < 27 * 128; i += 256) wl[i] = w[i];
    __syncthreads();

    int l  = tid & 63;
    int wv = tid >> 6;
    float bv0 = bvec[l], bv1 = bvec[64 + l];
    int waveSlots = gridDim.x * 4;
    int trips = (N + waveSlots - 1) / waveSlots;
    float s0 = 0.f, q0 = 0.f, s1 = 0.f, q1 = 0.f;
    for (int it = 0; it < trips; ++it) {
        int n = (it * gridDim.x + blockIdx.x) * 4 + wv;
        if (n < N) {
            const float* xr = x + (size_t)n * 27;
            float a0 = bv0, a1 = bv1;
            #pragma unroll
            for (int k = 0; k < 27; ++k) {
                float xv = xr[k];
                a0 = fmaf(xv, wl[k * 128 + l], a0);
                a1 = fmaf(xv, wl[k * 128 + 64 + l], a1);
            }
            outb[(size_t)n * 128 + l] = f2bf(a0);
            outb[(size_t)n * 128 + 64 + l] = f2bf(a1);
            s0 += a0; q0 += a0 * a0; s1 += a1; q1 += a1 * a1;
        }
    }
    __shared__ float sred[4][256];
    sred[0][tid] = s0; sred[1][tid] = q0;
    sred[2][tid] = s1; sred[3][tid] = q1;
    __syncthreads();
    if (tid < 64) {
        int t = tid;
        float v0 = sred[0][t] + sred[0][t + 64] + sred[0][t + 128] + sred[0][t + 192];
        float v1 = sred[1][t] + sred[1][t + 64] + sred[1][t + 128] + sred[1][t + 192];
        float v2 = sred[2][t] + sred[2][t + 64] + sred[2][t + 128] + sred[2][t + 192];
        float v3 = sred[3][t] + sred[3][t + 64] + sred[3][t + 128] + sred[3][t + 192];
        atomicAdd(stats + t, v0);
        atomicAdd(stats + 128 + t, v1);
        atomicAdd(stats + 64 + t, v2);
        atomicAdd(stats + 192 + t, v3);
    }
}

// ---------------------------------------------------------------- prep: hist + scan (last block) + gbound
__global__ __launch_bounds__(256)
void k_prep(const int* __restrict__ dst, int* __restrict__ bcnt, int* __restrict__ bbase,
            int E, int NB, int shift, const int* __restrict__ batch,
            int* __restrict__ gstart, int N, int G, int* __restrict__ arrive)
{
    const int HB = 256;
    int tid = threadIdx.x;
    __shared__ int hist[NBMAX];
    __shared__ int buf2[NBMAX];
    __shared__ int partl[256];
    __shared__ int lastf;

    if (blockIdx.x < HB) {
        for (int i = tid; i < NB; i += 256) hist[i] = 0;
        __syncthreads();
        int stride = HB * 256;
        for (int e = blockIdx.x * 256 + tid; e < E; e += stride)
            atomicAdd(&hist[dst[e] >> shift], 1);
        __syncthreads();
        for (int i = tid; i < NB; i += 256)
            if (hist[i]) atomicAdd(bcnt + i, hist[i]);
        __syncthreads();
        if (tid == 0) {
            __threadfence();
            int tk = atomicAdd(arrive, 1);
            lastf = (tk == HB - 1) ? 1 : 0;
        }
        __syncthreads();
        if (lastf) {
            __threadfence();
            int per = (NB + 255) / 256;
            int beg = tid * per, end = min(beg + per, NB);
            int s = 0;
            for (int i = beg; i < end; ++i) { int v = bcnt[i]; buf2[i] = s; s += v; }
            partl[tid] = s;
            __syncthreads();
            for (int ofs = 1; ofs < 256; ofs <<= 1) {
                int u = (tid >= ofs) ? partl[tid - ofs] : 0;
                __syncthreads();
                partl[tid] += u;
                __syncthreads();
            }
            int add = partl[tid] - s;
            for (int i = beg; i < end; ++i) bbase[i] = buf2[i] + add;
            if (tid == 0) bbase[NB] = E;
        }
    } else {
        int b = blockIdx.x - HB;
        int stride = (gridDim.x - HB) * 256;
        for (int n = b * 256 + tid; n < N; n += stride) {
            int bb = batch[n];
            if (n == 0) {
                for (int g = 0; g <= bb; ++g) gstart[g] = 0;
            } else {
                int pb = batch[n - 1];
                for (int g = pb + 1; g <= bb; ++g) gstart[g] = n;
            }
            if (n == N - 1) {
                for (int g = bb + 1; g <= G; ++g) gstart[g] = N;
            }
        }
    }
}

// ---------------------------------------------------------------- bucketed scatter
__global__ __launch_bounds__(256)
void k_p2_scatter(const int* __restrict__ src, const int* __restrict__ dst,
                  const int* __restrict__ bbase, int* __restrict__ bcur0,
                  uint2* __restrict__ bucketed, int E, int NB, int shift)
{
    __shared__ uint2 ebuf[CHUNK];
    __shared__ int hist[NBMAX];
    __shared__ int cur[NBMAX];
    __shared__ int wtmp[256];
    int tid = threadIdx.x;
    int c0 = blockIdx.x * CHUNK;
    int cc = min(CHUNK, E - c0);
    if (cc <= 0) return;

    for (int i = tid; i < NB; i += 256) hist[i] = 0;
    __syncthreads();
    for (int i = tid; i < cc; i += 256)
        atomicAdd(&hist[dst[c0 + i] >> shift], 1);
    __syncthreads();
    int per = (NB + 255) / 256;
    int beg = tid * per, end = min(beg + per, NB);
    int s = 0;
    for (int i = beg; i < end; ++i) s += hist[i];
    wtmp[tid] = s;
    __syncthreads();
    for (int ofs = 1; ofs < 256; ofs <<= 1) {
        int u = (tid >= ofs) ? wtmp[tid - ofs] : 0;
        __syncthreads();
        wtmp[tid] += u;
        __syncthreads();
    }
    int run = wtmp[tid] - s;
    for (int i = beg; i < end; ++i) { cur[i] = run; run += hist[i]; }
    __syncthreads();
    for (int i = tid; i < cc; i += 256) {
        int sv = src[c0 + i], dv = dst[c0 + i];
        int b = dv >> shift;
        int pos = atomicAdd(&cur[b], 1);
        ebuf[pos] = make_uint2((unsigned)sv, (unsigned)dv);
    }
    __syncthreads();
    for (int b = tid; b < NB; b += 256) {
        int c = hist[b];
        if (c > 0) {
            int lb = cur[b] - c;
            int gb = bbase[b] + atomicAdd(&bcur0[b], c);
            hist[b] = gb - lb;
        }
    }
    __syncthreads();
    for (int i = tid; i < cc; i += 256) {
        uint2 u = ebuf[i];
        int b = (int)(u.y >> shift);
        bucketed[hist[b] + i] = u;
    }
}

__global__ __launch_bounds__(256)
void k_p3_csr(const uint2* __restrict__ bucketed, const int* __restrict__ bbase,
              int* __restrict__ rowptr, int* __restrict__ csr,
              int N, int NB, int shift)
{
    __shared__ int ncnt[128], nsc[128];
    __shared__ int lcsr[CAP3];
    int b = blockIdx.x;
    int tid = threadIdx.x;
    int e0 = bbase[b], e1 = bbase[b + 1];
    int cnt = e1 - e0;
    int node0 = b << shift;
    int nodes = min(1 << shift, N - node0);

    if (tid < 128) ncnt[tid] = 0;
    __syncthreads();
    for (int i = tid; i < cnt; i += 256)
        atomicAdd(&ncnt[(int)bucketed[e0 + i].y - node0], 1);
    __syncthreads();
    if (tid < 128) nsc[tid] = ncnt[tid];
    __syncthreads();
    for (int ofs = 1; ofs < 128; ofs <<= 1) {
        int u = 0;
        if (tid < 128 && tid >= ofs) u = nsc[tid - ofs];
        __syncthreads();
        if (tid < 128) nsc[tid] += u;
        __syncthreads();
    }
    if (tid < nodes) rowptr[node0 + tid] = e0 + nsc[tid] - ncnt[tid];
    if (tid == 0 && b == NB - 1) rowptr[N] = e1;
    if (tid < 128) ncnt[tid] = nsc[tid] - ncnt[tid];
    __syncthreads();
    if (cnt <= CAP3) {
        for (int i = tid; i < cnt; i += 256) {
            uint2 u = bucketed[e0 + i];
            int d = (int)u.y - node0;
            int pos = atomicAdd(&ncnt[d], 1);
            lcsr[pos] = (int)u.x;
        }
        __syncthreads();
        for (int i = tid; i < cnt; i += 256) csr[e0 + i] = lcsr[i];
    } else {
        for (int i = tid; i < cnt; i += 256) {
            uint2 u = bucketed[e0 + i];
            int d = (int)u.y - node0;
            int pos = atomicAdd(&ncnt[d], 1);
            csr[e0 + pos] = (int)u.x;
        }
    }
}

// ---------------------------------------------------------------- fused BN + MFMA GEMM
__global__ __launch_bounds__(256)
void k_gemm_mfma(const unsigned short* __restrict__ tin, unsigned short* __restrict__ h,
                 const float* __restrict__ stats, const float* __restrict__ gamma,
                 const float* __restrict__ beta, float invN, int residual,
                 const float* __restrict__ basesW, const float* __restrict__ combW,
                 const float* __restrict__ combB,
                 unsigned short* __restrict__ basesP,
                 unsigned short* __restrict__ combB16, int N)
{
    __shared__ unsigned short Wlds[2560 * 8];   // 40 KB
    __shared__ float scL[128], shL[128];
    int tid = threadIdx.x;
    if (tid < 128) {
        float mu  = stats[tid] * invN;
        float var = stats[128 + tid] * invN - mu * mu;
        float sc  = gamma[tid] * rsqrtf(var + EPSV);
        scL[tid] = sc;
        shL[tid] = beta[tid] - mu * sc;
    }
    for (int i = tid; i < 2560; i += 256) {
        int ct = i >> 8, rem = i & 255;
        int ln = rem & 63;
        int n16 = ln & 15, quad = ln >> 4;
        int k = ((rem >> 6) << 5) + quad * 8;
        unsigned short tmp[8];
        if (ct < 4) {
            int c = ct * 16 + n16;
            #pragma unroll
            for (int j = 0; j < 8; ++j) tmp[j] = f2bf(basesW[(k + j) * 64 + c]);
        } else {
            int c = (ct - 4) * 16 + n16;
            #pragma unroll
            for (int j = 0; j < 8; ++j) tmp[j] = f2bf(combW[(k + j) * 96 + c]);
        }
        uint4 pk;
        pk.x = (unsigned)tmp[0] | ((unsigned)tmp[1] << 16);
        pk.y = (unsigned)tmp[2] | ((unsigned)tmp[3] << 16);
        pk.z = (unsigned)tmp[4] | ((unsigned)tmp[5] << 16);
        pk.w = (unsigned)tmp[6] | ((unsigned)tmp[7] << 16);
        *(uint4*)&Wlds[(size_t)i * 8] = pk;
    }
    __syncthreads();

    int lane = tid & 63, wv = tid >> 6;
    int f = lane & 15, quad = lane >> 4;
    float cbv[6];
    #pragma unroll
    for (int s = 0; s < 6; ++s) cbv[s] = combB[s * 16 + f];

    int tiles = (N + 15) >> 4;
    int waveSlots = gridDim.x * 4;
    for (int tile = blockIdx.x * 4 + wv; tile < tiles; tile += waveSlots) {
        int tb = tile * 16;
        int mnode = min(tb + f, N - 1);
        size_t rbase = (size_t)mnode * 128;

        f32x4 acc[10];
        #pragma unroll
        for (int ct = 0; ct < 10; ++ct) acc[ct] = (f32x4){0.f, 0.f, 0.f, 0.f};

        #pragma unroll
        for (int ki = 0; ki < 4; ++ki) {
            int kc = quad * 8 + ki * 32;
            uint4 tv = *(const uint4*)&tin[rbase + kc];
            float r0, r1, r2, r3, r4, r5, r6, r7;
            r0 = fmaxf(blo(tv.x) * scL[kc]     + shL[kc],     0.f);
            r1 = fmaxf(bhi(tv.x) * scL[kc + 1] + shL[kc + 1], 0.f);
            r2 = fmaxf(blo(tv.y) * scL[kc + 2] + shL[kc + 2], 0.f);
            r3 = fmaxf(bhi(tv.y) * scL[kc + 3] + shL[kc + 3], 0.f);
            r4 = fmaxf(blo(tv.z) * scL[kc + 4] + shL[kc + 4], 0.f);
            r5 = fmaxf(bhi(tv.z) * scL[kc + 5] + shL[kc + 5], 0.f);
            r6 = fmaxf(blo(tv.w) * scL[kc + 6] + shL[kc + 6], 0.f);
            r7 = fmaxf(bhi(tv.w) * scL[kc + 7] + shL[kc + 7], 0.f);
            if (residual) {
                uint4 hv = *(const uint4*)&h[rbase + kc];
                r0 += blo(hv.x); r1 += bhi(hv.x); r2 += blo(hv.y); r3 += bhi(hv.y);
                r4 += blo(hv.z); r5 += bhi(hv.z); r6 += blo(hv.w); r7 += bhi(hv.w);
            }
            unsigned short b0 = f2bf(r0), b1 = f2bf(r1), b2 = f2bf(r2), b3 = f2bf(r3);
            unsigned short b4 = f2bf(r4), b5 = f2bf(r5), b6 = f2bf(r6), b7 = f2bf(r7);
            uint4 hw;
            hw.x = (unsigned)b0 | ((unsigned)b1 << 16);
            hw.y = (unsigned)b2 | ((unsigned)b3 << 16);
            hw.z = (unsigned)b4 | ((unsigned)b5 << 16);
            hw.w = (unsigned)b6 | ((unsigned)b7 << 16);
            *(uint4*)&h[rbase + kc] = hw;
            short ab[8] = {(short)b0, (short)b1, (short)b2, (short)b3,
                           (short)b4, (short)b5, (short)b6, (short)b7};
            bf16x8 a = *(bf16x8*)ab;
            #pragma unroll
            for (int ct = 0; ct < 10; ++ct) {
                bf16x8 bfr = *(const bf16x8*)&Wlds[(size_t)((ct * 4 + ki) * 64 + lane) * 8];
                acc[ct] = __builtin_amdgcn_mfma_f32_16x16x32_bf16(a, bfr, acc[ct], 0, 0, 0);
            }
        }

        #pragma unroll
        for (int r = 0; r < 4; ++r) {
            int node = tb + quad * 4 + r;
            if (node < N) {
                #pragma unroll
                for (int ct = 0; ct < 4; ++ct)
                    basesP[(size_t)node * 64 + f * 4 + ct] = f2bf(acc[ct][r]);
                #pragma unroll
                for (int s = 0; s < 6; ++s)
                    combB16[(size_t)node * 96 + s * 16 + f] = f2bf(acc[4 + s][r] + cbv[s]);
            }
        }
    }
}

// ---------------------------------------------------------------- aggregation (two nodes/wave)
__global__ __launch_bounds__(256)
void k_agg(const unsigned short* __restrict__ basesP, const unsigned short* __restrict__ combB16,
           const int* __restrict__ csr, const int* __restrict__ rowptr,
           const float* __restrict__ cbias, unsigned short* __restrict__ outb,
           float* __restrict__ stats, int N)
{
    int l = threadIdx.x & 63;
    int w = threadIdx.x >> 6;
    int f = l & 15, sub = l >> 4;
    const char* bp = (const char*)basesP;
    unsigned fof = (unsigned)(f << 3);
    float cb0 = cbias[l], cb1 = cbias[64 + l];
    int waveSlots = gridDim.x * 4;
    int pairs = (N + 1) >> 1;
    int trips = (pairs + waveSlots - 1) / waveSlots;
    float s0 = 0.f, q0 = 0.f, s1 = 0.f, q1 = 0.f;

    for (int it = 0; it < trips; ++it) {
        int pr = (it * gridDim.x + blockIdx.x) * 4 + w;
        if (pr < pairs) {
            int nA = pr * 2;
            bool hasB = (nA + 1) < N;
            int nB = hasB ? nA + 1 : nA;
            int rA = rowptr[nA];
            int cA = rowptr[nA + 1] - rA;
            int rB = rowptr[nB];
            int cB = hasB ? (rowptr[nB + 1] - rB) : 0;

            float SA0 = 0.f, SA1 = 0.f, SA2 = 0.f, SA3 = 0.f;
            float MA0 = NEGINF, MA1 = NEGINF, MA2 = NEGINF, MA3 = NEGINF;
            float SB0 = 0.f, SB1 = 0.f, SB2 = 0.f, SB3 = 0.f;
            float MB0 = NEGINF, MB1 = NEGINF, MB2 = NEGINF, MB3 = NEGINF;

            int mt = (max(cA, cB) + 3) >> 2;
            int e = sub;
            #pragma unroll 2
            for (int t = 0; t < mt; ++t) {
                int eA = max(min(e, cA - 1), 0);
                int eB = max(min(e, cB - 1), 0);
                int snA = csr[rA + eA];
                int snB = csr[rB + eB];
                uint2 uA = *(const uint2*)(bp + (((unsigned)snA) << 7) + fof);
                uint2 uB = *(const uint2*)(bp + (((unsigned)snB) << 7) + fof);
                bool vA = e < cA, vB = e < cB;
                float a0 = blo(uA.x), a1 = bhi(uA.x), a2 = blo(uA.y), a3 = bhi(uA.y);
                float b0 = blo(uB.x), b1 = bhi(uB.x), b2 = blo(uB.y), b3 = bhi(uB.y);
                SA0 += vA ? a0 : 0.f; SA1 += vA ? a1 : 0.f;
                SA2 += vA ? a2 : 0.f; SA3 += vA ? a3 : 0.f;
                MA0 = fmaxf(MA0, vA ? a0 : NEGINF); MA1 = fmaxf(MA1, vA ? a1 : NEGINF);
                MA2 = fmaxf(MA2, vA ? a2 : NEGINF); MA3 = fmaxf(MA3, vA ? a3 : NEGINF);
                SB0 += vB ? b0 : 0.f; SB1 += vB ? b1 : 0.f;
                SB2 += vB ? b2 : 0.f; SB3 += vB ? b3 : 0.f;
                MB0 = fmaxf(MB0, vB ? b0 : NEGINF); MB1 = fmaxf(MB1, vB ? b1 : NEGINF);
                MB2 = fmaxf(MB2, vB ? b2 : NEGINF); MB3 = fmaxf(MB3, vB ? b3 : NEGINF);
                e += 4;
            }

            #pragma unroll
            for (int m = 0; m < 2; ++m) {
                if (m == 1 && !hasB) break;
                int n = (m == 0) ? nA : nB;
                int cnt = (m == 0) ? cA : cB;
                float T0 = (m == 0) ? SA0 : SB0, T1 = (m == 0) ? SA1 : SB1;
                float T2 = (m == 0) ? SA2 : SB2, T3 = (m == 0) ? SA3 : SB3;
                float X0 = (m == 0) ? MA0 : MB0, X1 = (m == 0) ? MA1 : MB1;
                float X2 = (m == 0) ? MA2 : MB2, X3 = (m == 0) ? MA3 : MB3;
                T0 += __shfl_xor(T0, 16, 64); T1 += __shfl_xor(T1, 16, 64);
                T2 += __shfl_xor(T2, 16, 64); T3 += __shfl_xor(T3, 16, 64);
                T0 += __shfl_xor(T0, 32, 64); T1 += __shfl_xor(T1, 32, 64);
                T2 += __shfl_xor(T2, 32, 64); T3 += __shfl_xor(T3, 32, 64);
                X0 = fmaxf(X0, __shfl_xor(X0, 16, 64)); X1 = fmaxf(X1, __shfl_xor(X1, 16, 64));
                X2 = fmaxf(X2, __shfl_xor(X2, 16, 64)); X3 = fmaxf(X3, __shfl_xor(X3, 16, 64));
                X0 = fmaxf(X0, __shfl_xor(X0, 32, 64)); X1 = fmaxf(X1, __shfl_xor(X1, 32, 64));
                X2 = fmaxf(X2, __shfl_xor(X2, 32, 64)); X3 = fmaxf(X3, __shfl_xor(X3, 32, 64));
                uint2 su = *(const uint2*)(bp + (((unsigned)n) << 7) + fof);
                float w0 = blo(su.x), w1 = bhi(su.x), w2 = blo(su.y), w3 = bhi(su.y);
                T0 += w0; T1 += w1; T2 += w2; T3 += w3;
                X0 = fmaxf(X0, w0); X1 = fmaxf(X1, w1);
                X2 = fmaxf(X2, w2); X3 = fmaxf(X3, w3);
                float invd = 1.f / (float)(cnt + 1);
                float A0 = T0 * invd, A1 = T1 * invd, A2 = T2 * invd, A3 = T3 * invd;

                const unsigned short* cr = combB16 + (size_t)n * 96;
                const uint2* c0p = (const uint2*)(cr + sub * 12);
                const uint2* c1p = (const uint2*)(cr + 48 + sub * 12);
                uint2 qa0 = c0p[0], qa1 = c0p[1], qa2 = c0p[2];
                uint2 qb0 = c1p[0], qb1 = c1p[1], qb2 = c1p[2];

                float o0 = cb0, o1 = cb1;
                o0 = fmaf(blo(qa0.x), T0, o0); o0 = fmaf(bhi(qa0.x), T1, o0);
                o0 = fmaf(blo(qa0.y), T2, o0); o0 = fmaf(bhi(qa0.y), T3, o0);
                o0 = fmaf(blo(qa1.x), A0, o0); o0 = fmaf(bhi(qa1.x), A1, o0);
                o0 = fmaf(blo(qa1.y), A2, o0); o0 = fmaf(bhi(qa1.y), A3, o0);
                o0 = fmaf(blo(qa2.x), X0, o0); o0 = fmaf(bhi(qa2.x), X1, o0);
                o0 = fmaf(blo(qa2.y), X2, o0); o0 = fmaf(bhi(qa2.y), X3, o0);
                o1 = fmaf(blo(qb0.x), T0, o1); o1 = fmaf(bhi(qb0.x), T1, o1);
                o1 = fmaf(blo(qb0.y), T2, o1); o1 = fmaf(bhi(qb0.y), T3, o1);
                o1 = fmaf(blo(qb1.x), A0, o1); o1 = fmaf(bhi(qb1.x), A1, o1);
                o1 = fmaf(blo(qb1.y), A2, o1); o1 = fmaf(bhi(qb1.y), A3, o1);
                o1 = fmaf(blo(qb2.x), X0, o1); o1 = fmaf(bhi(qb2.x), X1, o1);
                o1 = fmaf(blo(qb2.y), X2, o1); o1 = fmaf(bhi(qb2.y), X3, o1);

                outb[(size_t)n * 128 + l] = f2bf(o0);
                outb[(size_t)n * 128 + 64 + l] = f2bf(o1);
                s0 += o0; q0 += o0 * o0; s1 += o1; q1 += o1 * o1;
            }
        }
    }
    __shared__ float sred[4][256];
    sred[0][threadIdx.x] = s0; sred[1][threadIdx.x] = q0;
    sred[2][threadIdx.x] = s1; sred[3][threadIdx.x] = q1;
    __syncthreads();
    if (threadIdx.x < 64) {
        int t = threadIdx.x;
        float v0 = sred[0][t] + sred[0][t + 64] + sred[0][t + 128] + sred[0][t + 192];
        float v1 = sred[1][t] + sred[1][t + 64] + sred[1][t + 128] + sred[1][t + 192];
        float v2 = sred[2][t] + sred[2][t + 64] + sred[2][t + 128] + sred[2][t + 192];
        float v3 = sred[3][t] + sred[3][t + 64] + sred[3][t + 128] + sred[3][t + 192];
        atomicAdd(stats + t, v0);
        atomicAdd(stats + 128 + t, v1);
        atomicAdd(stats + 64 + t, v2);
        atomicAdd(stats + 192 + t, v3);
    }
}

// ---------------------------------------------------------------- pooling (fused final BN)
__global__ __launch_bounds__(256)
void k_gmean(const unsigned short* __restrict__ t, const unsigned short* __restrict__ h,
             const float* __restrict__ stats, const float* __restrict__ gamma,
             const float* __restrict__ beta, float invN,
             const int* __restrict__ gstart, float* __restrict__ gout, int G)
{
    __shared__ float part[128];
    int g = blockIdx.x;
    if (g >= G) return;
    int c = threadIdx.x & 127;
    int half = threadIdx.x >> 7;
    float mu  = stats[c] * invN;
    float var = stats[128 + c] * invN - mu * mu;
    float sc  = gamma[c] * rsqrtf(var + EPSV);
    float sh  = beta[c] - mu * sc;
    int s = gstart[g], e = gstart[g + 1];
    float acc = 0.f;
    #pragma unroll 2
    for (int n = s + half; n < e; n += 2) {
        size_t o = (size_t)n * 128 + c;
        acc += bfu(h[o]) + fmaxf(bfu(t[o]) * sc + sh, 0.f);
    }
    if (half) part[c] = acc;
    __syncthreads();
    if (!half) {
        float tot = acc + part[c];
        float cntf = fmaxf((float)(e - s), 1.f);
        gout[g * 128 + c] = tot / cntf;
    }
}

// ---------------------------------------------------------------- MLP
__global__ void k_mlp1(const float* __restrict__ gin, const float* __restrict__ w1,
                       float* __restrict__ t1, float* __restrict__ stats, int G)
{
    int g = blockIdx.x;
    int c = threadIdx.x;
    const float* gr = gin + g * 128;
    float acc = 0.f;
    for (int k = 0; k < 128; ++k) acc = fmaf(gr[k], w1[k * 64 + c], acc);
    t1[g * 64 + c] = acc;
    atomicAdd(stats + c, acc);
    atomicAdd(stats + 64 + c, acc * acc);
}

__global__ void k_mlp2(const float* __restrict__ t1, const float* __restrict__ stats1,
                       const float* __restrict__ g1, const float* __restrict__ b1,
                       const float* __restrict__ w2, float* __restrict__ t2,
                       float* __restrict__ stats2, float invG, int G)
{
    __shared__ float row[64];
    int g = blockIdx.x;
    int c = threadIdx.x;
    float v = t1[g * 64 + c];
    float mu = stats1[c] * invG;
    float var = stats1[64 + c] * invG - mu * mu;
    row[c] = fmaxf(g1[c] * (v - mu) * rsqrtf(var + EPSV) + b1[c], 0.f);
    __syncthreads();
    if (c < 32) {
        float acc = 0.f;
        #pragma unroll
        for (int k = 0; k < 64; ++k) acc = fmaf(row[k], w2[k * 32 + c], acc);
        t2[g * 32 + c] = acc;
        atomicAdd(stats2 + c, acc);
        atomicAdd(stats2 + 32 + c, acc * acc);
    }
}

__global__ void k_mlp3(const float* __restrict__ t2, const float* __restrict__ stats2,
                       const float* __restrict__ g2, const float* __restrict__ b2,
                       const float* __restrict__ w3, const float* __restrict__ b3,
                       float* __restrict__ out, float invG, int G)
{
    __shared__ float row[32];
    int g = blockIdx.x;
    int c = threadIdx.x;
    if (c < 32) {
        float v = t2[g * 32 + c];
        float mu = stats2[c] * invG;
        float var = stats2[32 + c] * invG - mu * mu;
        row[c] = fmaxf(g2[c] * (v - mu) * rsqrtf(var + EPSV) + b2[c], 0.f);
    }
    __syncthreads();
    if (c < 10) {
        float acc = b3[c];
        #pragma unroll
        for (int k = 0; k < 32; ++k) acc = fmaf(row[k], w3[k * 10 + c], acc);
        out[g * 10 + c] = acc;
    }
}

// ---------------------------------------------------------------- launch
extern "C" void kernel_launch(void* const* d_in, const int* in_sizes, int n_in,
                              void* d_out, int out_size, void* d_ws, size_t ws_size,
                              hipStream_t stream)
{
    const float* x        = (const float*)d_in[0];
    const float* lin1_w   = (const float*)d_in[1];
    const float* lin1_b   = (const float*)d_in[2];
    const float* bn1_g    = (const float*)d_in[3];
    const float* bn1_b    = (const float*)d_in[4];
    const float* bases_w  = (const float*)d_in[5];
    const float* comb_w   = (const float*)d_in[6];
    const float* comb_b   = (const float*)d_in[7];
    const float* conv_bias= (const float*)d_in[8];
    const float* bn_g     = (const float*)d_in[9];
    const float* bn_b     = (const float*)d_in[10];
    const float* mlp_w1   = (const float*)d_in[11];
    const float* mbn1_g   = (const float*)d_in[12];
    const float* mbn1_b   = (const float*)d_in[13];
    const float* mlp_w2   = (const float*)d_in[14];
    const float* mbn2_g   = (const float*)d_in[15];
    const float* mbn2_b   = (const float*)d_in[16];
    const float* mlp_w3   = (const float*)d_in[17];
    const float* mlp_b3   = (const float*)d_in[18];
    const int*   edge_idx = (const int*)d_in[19];
    const int*   batch    = (const int*)d_in[20];
    float* outp = (float*)d_out;

    const int N = in_sizes[20];
    const int E = in_sizes[19] / 2;
    const int G = out_size / 10;
    const int* esrc = edge_idx;
    const int* edst = edge_idx + E;

    int shift = 6;
    while ((((N - 1) >> shift) + 1) > NBMAX && shift < 7) ++shift;
    const int NB = ((N - 1) >> shift) + 1;

    char* p = (char*)d_ws;
    auto alloc = [&](size_t bytes) {
        char* r = p;
        p += (bytes + 255) & ~(size_t)255;
        return r;
    };
    unsigned short* h      = (unsigned short*)alloc((size_t)N * 128 * 2);
    unsigned short* basesP = (unsigned short*)alloc((size_t)N * 64 * 2);
    unsigned short* combB16= (unsigned short*)alloc((size_t)N * 96 * 2);
    unsigned short* outb   = (unsigned short*)alloc((size_t)N * 128 * 2);
    int*            csr    = (int*)  alloc((size_t)(E + 64) * 4);
    int*            rowptr = (int*)  alloc((size_t)(N + 1) * 4);
    int*            bbase  = (int*)  alloc((size_t)(NB + 1) * 4);
    float*          tg     = (float*)alloc((size_t)G * 128 * 4);
    float*          t1     = (float*)alloc((size_t)G * 64 * 4);
    float*          t2     = (float*)alloc((size_t)G * 32 * 4);
    int*            gstart = (int*)  alloc((size_t)(G + 1) * 4);
    char*           zbase  = p;
    int*            bcnt   = (int*)  alloc((size_t)NB * 4);
    int*            bcur0  = (int*)  alloc((size_t)NB * 4);
    float*          stats  = (float*)alloc(7 * 256 * 4);
    int*            arrive = (int*)  alloc(2 * 4);
    size_t zbytes = (size_t)(p - zbase);
    uint2* bucketed = (uint2*)combB16;   // alias: CSR build done before gemm writes
    (void)ws_size; (void)n_in;

    hipMemsetAsync(zbase, 0, zbytes, stream);

    const float invN = 1.0f / (float)N;
    const float invG = 1.0f / (float)G;

    k_lin1<<<1024, 256, 0, stream>>>(x, lin1_w, lin1_b, outb, stats, N);
    k_prep<<<768, 256, 0, stream>>>(edst, bcnt, bbase, E, NB, shift,
                                    batch, gstart, N, G, arrive);
    k_p2_scatter<<<(E + CHUNK - 1) / CHUNK, 256, 0, stream>>>(esrc, edst, bbase, bcur0,
                                                              bucketed, E, NB, shift);
    k_p3_csr<<<NB, 256, 0, stream>>>(bucketed, bbase, rowptr, csr, N, NB, shift);

    for (int l = 0; l < 4; ++l) {
        const float* bw = bases_w + (size_t)l * 128 * 64;
        const float* cw = comb_w + (size_t)l * 128 * 96;
        const float* cb = comb_b + (size_t)l * 96;
        const float* cvb = conv_bias + (size_t)l * 128;
        const float* pg = (l == 0) ? bn1_g : bn_g + (l - 1) * 128;
        const float* pb = (l == 0) ? bn1_b : bn_b + (l - 1) * 128;
        k_gemm_mfma<<<1024, 256, 0, stream>>>(outb, h, stats + l * 256, pg, pb, invN,
                                              l > 0 ? 1 : 0, bw, cw, cb, basesP, combB16, N);
        k_agg<<<2048, 256, 0, stream>>>(basesP, combB16, csr, rowptr, cvb,
                                        outb, stats + (1 + l) * 256, N);
    }

    k_gmean<<<G, 256, 0, stream>>>(outb, h, stats + 4 * 256, bn_g + 3 * 128,
                                   bn_b + 3 * 128, invN, gstart, tg, G);
    float* st5 = stats + 5 * 256;
    float* st6 = stats + 6 * 256;
    k_mlp1<<<G, 64, 0, stream>>>(tg, mlp_w1, t1, st5, G);
    k_mlp2<<<G, 64, 0, stream>>>(t1, st5, mbn1_g, mbn1_b, mlp_w2, t2, st6, invG, G);
    k_mlp3<<<G, 64, 0, stream>>>(t2, st6, mbn2_g, mbn2_b, mlp_w3, mlp_b3, outp, invG, G);
}

// Round 12
// 771.304 us; speedup vs baseline: 1.2738x; 1.0588x over previous
//
#include <hip/hip_runtime.h>

#define EPSV 1e-5f
#define NEGINF -3.402823466e38f
#define NBMAX 1600
#define CHUNK 4096
#define CAP3 6144

typedef short bf16x8 __attribute__((ext_vector_type(8)));
typedef float f32x4 __attribute__((ext_vector_type(4)));

__device__ __forceinline__ unsigned short f2bf(float f) {
    union { float f; unsigned i; } c; c.f = f;
    unsigned r = c.i + 0x7fff + ((c.i >> 16) & 1);
    return (unsigned short)(r >> 16);
}
__device__ __forceinline__ float blo(unsigned u) {
    union { unsigned i; float f; } c; c.i = u << 16; return c.f;
}
__device__ __forceinline__ float bhi(unsigned u) {
    union { unsigned i; float f; } c; c.i = u & 0xffff0000u; return c.f;
}
__device__ __forceinline__ float bfu(unsigned short u) {
    union { unsigned i; float f; } c; c.i = ((unsigned)u) << 16; return c.f;
}

// ---------------------------------------------------------------- lin1 + stats
__global__ __launch_bounds__(256)
void k_lin1(const float* __restrict__ x, const float* __restrict__ w,
            const float* __restrict__ bvec, unsigned short* __restrict__ outb,
            float* __restrict__ stats, int N)
{
    __shared__ float wl[27 * 128];
    int tid = threadIdx.x;
    for (int i = tid; i < 27 * 128; i += 256) wl[i] = w[i];
    __syncthreads();

    int l  = tid & 63;
    int wv = tid >> 6;
    float bv0 = bvec[l], bv1 = bvec[64 + l];
    int waveSlots = gridDim.x * 4;
    int trips = (N + waveSlots - 1) / waveSlots;
    float s0 = 0.f, q0 = 0.f, s1 = 0.f, q1 = 0.f;
    for (int it = 0; it < trips; ++it) {
        int n = (it * gridDim.x + blockIdx.x) * 4 + wv;
        if (n < N) {
            const float* xr = x + (size_t)n * 27;
            float a0 = bv0, a1 = bv1;
            #pragma unroll
            for (int k = 0; k < 27; ++k) {
                float xv = xr[k];
                a0 = fmaf(xv, wl[k * 128 + l], a0);
                a1 = fmaf(xv, wl[k * 128 + 64 + l], a1);
            }
            outb[(size_t)n * 128 + l] = f2bf(a0);
            outb[(size_t)n * 128 + 64 + l] = f2bf(a1);
            s0 += a0; q0 += a0 * a0; s1 += a1; q1 += a1 * a1;
        }
    }
    __shared__ float sred[4][256];
    sred[0][tid] = s0; sred[1][tid] = q0;
    sred[2][tid] = s1; sred[3][tid] = q1;
    __syncthreads();
    if (tid < 64) {
        int t = tid;
        float v0 = sred[0][t] + sred[0][t + 64] + sred[0][t + 128] + sred[0][t + 192];
        float v1 = sred[1][t] + sred[1][t + 64] + sred[1][t + 128] + sred[1][t + 192];
        float v2 = sred[2][t] + sred[2][t + 64] + sred[2][t + 128] + sred[2][t + 192];
        float v3 = sred[3][t] + sred[3][t + 64] + sred[3][t + 128] + sred[3][t + 192];
        atomicAdd(stats + t, v0);
        atomicAdd(stats + 128 + t, v1);
        atomicAdd(stats + 64 + t, v2);
        atomicAdd(stats + 192 + t, v3);
    }
}

// ---------------------------------------------------------------- prep: hist + scan (last block) + gbound
__global__ __launch_bounds__(256)
void k_prep(const int* __restrict__ dst, int* __restrict__ bcnt, int* __restrict__ bbase,
            int E, int NB, int shift, const int* __restrict__ batch,
            int* __restrict__ gstart, int N, int G, int* __restrict__ arrive)
{
    const int HB = 256;
    int tid = threadIdx.x;
    __shared__ int hist[NBMAX];
    __shared__ int buf2[NBMAX];
    __shared__ int partl[256];
    __shared__ int lastf;

    if (blockIdx.x < HB) {
        for (int i = tid; i < NB; i += 256) hist[i] = 0;
        __syncthreads();
        int stride = HB * 256;
        for (int e = blockIdx.x * 256 + tid; e < E; e += stride)
            atomicAdd(&hist[dst[e] >> shift], 1);
        __syncthreads();
        for (int i = tid; i < NB; i += 256)
            if (hist[i]) atomicAdd(bcnt + i, hist[i]);
        __syncthreads();
        if (tid == 0) {
            __threadfence();
            int tk = atomicAdd(arrive, 1);
            lastf = (tk == HB - 1) ? 1 : 0;
        }
        __syncthreads();
        if (lastf) {
            __threadfence();
            int per = (NB + 255) / 256;
            int beg = tid * per, end = min(beg + per, NB);
            int s = 0;
            for (int i = beg; i < end; ++i) { int v = bcnt[i]; buf2[i] = s; s += v; }
            partl[tid] = s;
            __syncthreads();
            for (int ofs = 1; ofs < 256; ofs <<= 1) {
                int u = (tid >= ofs) ? partl[tid - ofs] : 0;
                __syncthreads();
                partl[tid] += u;
                __syncthreads();
            }
            int add = partl[tid] - s;
            for (int i = beg; i < end; ++i) bbase[i] = buf2[i] + add;
            if (tid == 0) bbase[NB] = E;
        }
    } else {
        int b = blockIdx.x - HB;
        int stride = (gridDim.x - HB) * 256;
        for (int n = b * 256 + tid; n < N; n += stride) {
            int bb = batch[n];
            if (n == 0) {
                for (int g = 0; g <= bb; ++g) gstart[g] = 0;
            } else {
                int pb = batch[n - 1];
                for (int g = pb + 1; g <= bb; ++g) gstart[g] = n;
            }
            if (n == N - 1) {
                for (int g = bb + 1; g <= G; ++g) gstart[g] = N;
            }
        }
    }
}

// ---------------------------------------------------------------- bucketed scatter
__global__ __launch_bounds__(256)
void k_p2_scatter(const int* __restrict__ src, const int* __restrict__ dst,
                  const int* __restrict__ bbase, int* __restrict__ bcur0,
                  uint2* __restrict__ bucketed, int E, int NB, int shift)
{
    __shared__ uint2 ebuf[CHUNK];
    __shared__ int hist[NBMAX];
    __shared__ int cur[NBMAX];
    __shared__ int wtmp[256];
    int tid = threadIdx.x;
    int c0 = blockIdx.x * CHUNK;
    int cc = min(CHUNK, E - c0);
    if (cc <= 0) return;

    for (int i = tid; i < NB; i += 256) hist[i] = 0;
    __syncthreads();
    for (int i = tid; i < cc; i += 256)
        atomicAdd(&hist[dst[c0 + i] >> shift], 1);
    __syncthreads();
    int per = (NB + 255) / 256;
    int beg = tid * per, end = min(beg + per, NB);
    int s = 0;
    for (int i = beg; i < end; ++i) s += hist[i];
    wtmp[tid] = s;
    __syncthreads();
    for (int ofs = 1; ofs < 256; ofs <<= 1) {
        int u = (tid >= ofs) ? wtmp[tid - ofs] : 0;
        __syncthreads();
        wtmp[tid] += u;
        __syncthreads();
    }
    int run = wtmp[tid] - s;
    for (int i = beg; i < end; ++i) { cur[i] = run; run += hist[i]; }
    __syncthreads();
    for (int i = tid; i < cc; i += 256) {
        int sv = src[c0 + i], dv = dst[c0 + i];
        int b = dv >> shift;
        int pos = atomicAdd(&cur[b], 1);
        ebuf[pos] = make_uint2((unsigned)sv, (unsigned)dv);
    }
    __syncthreads();
    for (int b = tid; b < NB; b += 256) {
        int c = hist[b];
        if (c > 0) {
            int lb = cur[b] - c;
            int gb = bbase[b] + atomicAdd(&bcur0[b], c);
            hist[b] = gb - lb;
        }
    }
    __syncthreads();
    for (int i = tid; i < cc; i += 256) {
        uint2 u = ebuf[i];
        int b = (int)(u.y >> shift);
        bucketed[hist[b] + i] = u;
    }
}

__global__ __launch_bounds__(256)
void k_p3_csr(const uint2* __restrict__ bucketed, const int* __restrict__ bbase,
              int* __restrict__ rowptr, int* __restrict__ csr,
              int N, int NB, int shift)
{
    __shared__ int ncnt[128], nsc[128];
    __shared__ int lcsr[CAP3];
    int b = blockIdx.x;
    int tid = threadIdx.x;
    int e0 = bbase[b], e1 = bbase[b + 1];
    int cnt = e1 - e0;
    int node0 = b << shift;
    int nodes = min(1 << shift, N - node0);

    if (tid < 128) ncnt[tid] = 0;
    __syncthreads();
    for (int i = tid; i < cnt; i += 256)
        atomicAdd(&ncnt[(int)bucketed[e0 + i].y - node0], 1);
    __syncthreads();
    if (tid < 128) nsc[tid] = ncnt[tid];
    __syncthreads();
    for (int ofs = 1; ofs < 128; ofs <<= 1) {
        int u = 0;
        if (tid < 128 && tid >= ofs) u = nsc[tid - ofs];
        __syncthreads();
        if (tid < 128) nsc[tid] += u;
        __syncthreads();
    }
    if (tid < nodes) rowptr[node0 + tid] = e0 + nsc[tid] - ncnt[tid];
    if (tid == 0 && b == NB - 1) rowptr[N] = e1;
    if (tid < 128) ncnt[tid] = nsc[tid] - ncnt[tid];
    __syncthreads();
    if (cnt <= CAP3) {
        for (int i = tid; i < cnt; i += 256) {
            uint2 u = bucketed[e0 + i];
            int d = (int)u.y - node0;
            int pos = atomicAdd(&ncnt[d], 1);
            lcsr[pos] = (int)u.x;
        }
        __syncthreads();
        for (int i = tid; i < cnt; i += 256) csr[e0 + i] = lcsr[i];
    } else {
        for (int i = tid; i < cnt; i += 256) {
            uint2 u = bucketed[e0 + i];
            int d = (int)u.y - node0;
            int pos = atomicAdd(&ncnt[d], 1);
            csr[e0 + pos] = (int)u.x;
        }
    }
}

// ---------------------------------------------------------------- fused BN + MFMA GEMM
__global__ __launch_bounds__(256)
void k_gemm_mfma(const unsigned short* __restrict__ tin, unsigned short* __restrict__ h,
                 const float* __restrict__ stats, const float* __restrict__ gamma,
                 const float* __restrict__ beta, float invN, int residual,
                 const float* __restrict__ basesW, const float* __restrict__ combW,
                 const float* __restrict__ combB,
                 unsigned short* __restrict__ basesP,
                 unsigned short* __restrict__ combB16, int N)
{
    __shared__ unsigned short Wlds[2560 * 8];   // 40 KB
    __shared__ float scL[128], shL[128];
    int tid = threadIdx.x;
    if (tid < 128) {
        float mu  = stats[tid] * invN;
        float var = stats[128 + tid] * invN - mu * mu;
        float sc  = gamma[tid] * rsqrtf(var + EPSV);
        scL[tid] = sc;
        shL[tid] = beta[tid] - mu * sc;
    }
    for (int i = tid; i < 2560; i += 256) {
        int ct = i >> 8, rem = i & 255;
        int ln = rem & 63;
        int n16 = ln & 15, quad = ln >> 4;
        int k = ((rem >> 6) << 5) + quad * 8;
        unsigned short tmp[8];
        if (ct < 4) {
            int c = ct * 16 + n16;
            #pragma unroll
            for (int j = 0; j < 8; ++j) tmp[j] = f2bf(basesW[(k + j) * 64 + c]);
        } else {
            int c = (ct - 4) * 16 + n16;
            #pragma unroll
            for (int j = 0; j < 8; ++j) tmp[j] = f2bf(combW[(k + j) * 96 + c]);
        }
        uint4 pk;
        pk.x = (unsigned)tmp[0] | ((unsigned)tmp[1] << 16);
        pk.y = (unsigned)tmp[2] | ((unsigned)tmp[3] << 16);
        pk.z = (unsigned)tmp[4] | ((unsigned)tmp[5] << 16);
        pk.w = (unsigned)tmp[6] | ((unsigned)tmp[7] << 16);
        *(uint4*)&Wlds[(size_t)i * 8] = pk;
    }
    __syncthreads();

    int lane = tid & 63, wv = tid >> 6;
    int f = lane & 15, quad = lane >> 4;
    float cbv[6];
    #pragma unroll
    for (int s = 0; s < 6; ++s) cbv[s] = combB[s * 16 + f];

    int tiles = (N + 15) >> 4;
    int waveSlots = gridDim.x * 4;
    for (int tile = blockIdx.x * 4 + wv; tile < tiles; tile += waveSlots) {
        int tb = tile * 16;
        int mnode = min(tb + f, N - 1);
        size_t rbase = (size_t)mnode * 128;

        f32x4 acc[10];
        #pragma unroll
        for (int ct = 0; ct < 10; ++ct) acc[ct] = (f32x4){0.f, 0.f, 0.f, 0.f};

        #pragma unroll
        for (int ki = 0; ki < 4; ++ki) {
            int kc = quad * 8 + ki * 32;
            uint4 tv = *(const uint4*)&tin[rbase + kc];
            float r0, r1, r2, r3, r4, r5, r6, r7;
            r0 = fmaxf(blo(tv.x) * scL[kc]     + shL[kc],     0.f);
            r1 = fmaxf(bhi(tv.x) * scL[kc + 1] + shL[kc + 1], 0.f);
            r2 = fmaxf(blo(tv.y) * scL[kc + 2] + shL[kc + 2], 0.f);
            r3 = fmaxf(bhi(tv.y) * scL[kc + 3] + shL[kc + 3], 0.f);
            r4 = fmaxf(blo(tv.z) * scL[kc + 4] + shL[kc + 4], 0.f);
            r5 = fmaxf(bhi(tv.z) * scL[kc + 5] + shL[kc + 5], 0.f);
            r6 = fmaxf(blo(tv.w) * scL[kc + 6] + shL[kc + 6], 0.f);
            r7 = fmaxf(bhi(tv.w) * scL[kc + 7] + shL[kc + 7], 0.f);
            if (residual) {
                uint4 hv = *(const uint4*)&h[rbase + kc];
                r0 += blo(hv.x); r1 += bhi(hv.x); r2 += blo(hv.y); r3 += bhi(hv.y);
                r4 += blo(hv.z); r5 += bhi(hv.z); r6 += blo(hv.w); r7 += bhi(hv.w);
            }
            unsigned short b0 = f2bf(r0), b1 = f2bf(r1), b2 = f2bf(r2), b3 = f2bf(r3);
            unsigned short b4 = f2bf(r4), b5 = f2bf(r5), b6 = f2bf(r6), b7 = f2bf(r7);
            uint4 hw;
            hw.x = (unsigned)b0 | ((unsigned)b1 << 16);
            hw.y = (unsigned)b2 | ((unsigned)b3 << 16);
            hw.z = (unsigned)b4 | ((unsigned)b5 << 16);
            hw.w = (unsigned)b6 | ((unsigned)b7 << 16);
            *(uint4*)&h[rbase + kc] = hw;
            short ab[8] = {(short)b0, (short)b1, (short)b2, (short)b3,
                           (short)b4, (short)b5, (short)b6, (short)b7};
            bf16x8 a = *(bf16x8*)ab;
            #pragma unroll
            for (int ct = 0; ct < 10; ++ct) {
                bf16x8 bfr = *(const bf16x8*)&Wlds[(size_t)((ct * 4 + ki) * 64 + lane) * 8];
                acc[ct] = __builtin_amdgcn_mfma_f32_16x16x32_bf16(a, bfr, acc[ct], 0, 0, 0);
            }
        }

        #pragma unroll
        for (int r = 0; r < 4; ++r) {
            int node = tb + quad * 4 + r;
            if (node < N) {
                // packed bases store: 4 consecutive shorts = one uint2
                uint2 bpk;
                bpk.x = (unsigned)f2bf(acc[0][r]) | ((unsigned)f2bf(acc[1][r]) << 16);
                bpk.y = (unsigned)f2bf(acc[2][r]) | ((unsigned)f2bf(acc[3][r]) << 16);
                *(uint2*)&basesP[(size_t)node * 64 + f * 4] = bpk;
                #pragma unroll
                for (int s = 0; s < 6; ++s)
                    combB16[(size_t)node * 96 + s * 16 + f] = f2bf(acc[4 + s][r] + cbv[s]);
            }
        }
    }
}

// ---------------------------------------------------------------- aggregation (two nodes/wave)
__global__ __launch_bounds__(256)
void k_agg(const unsigned short* __restrict__ basesP, const unsigned short* __restrict__ combB16,
           const int* __restrict__ csr, const int* __restrict__ rowptr,
           const float* __restrict__ cbias, unsigned short* __restrict__ outb,
           float* __restrict__ stats, int N)
{
    int l = threadIdx.x & 63;
    int w = threadIdx.x >> 6;
    int f = l & 15, sub = l >> 4;
    const char* bp = (const char*)basesP;
    unsigned fof = (unsigned)(f << 3);
    float cb0 = cbias[l], cb1 = cbias[64 + l];
    int waveSlots = gridDim.x * 4;
    int pairs = (N + 1) >> 1;
    int trips = (pairs + waveSlots - 1) / waveSlots;
    float s0 = 0.f, q0 = 0.f, s1 = 0.f, q1 = 0.f;

    for (int it = 0; it < trips; ++it) {
        int pr = (it * gridDim.x + blockIdx.x) * 4 + w;
        if (pr < pairs) {
            int nA = pr * 2;
            bool hasB = (nA + 1) < N;
            int nB = hasB ? nA + 1 : nA;
            int rA = rowptr[nA];
            int cA = rowptr[nA + 1] - rA;
            int rB = rowptr[nB];
            int cB = hasB ? (rowptr[nB + 1] - rB) : 0;

            float SA0 = 0.f, SA1 = 0.f, SA2 = 0.f, SA3 = 0.f;
            float MA0 = NEGINF, MA1 = NEGINF, MA2 = NEGINF, MA3 = NEGINF;
            float SB0 = 0.f, SB1 = 0.f, SB2 = 0.f, SB3 = 0.f;
            float MB0 = NEGINF, MB1 = NEGINF, MB2 = NEGINF, MB3 = NEGINF;

            int mt = (max(cA, cB) + 3) >> 2;
            int e = sub;
            #pragma unroll 2
            for (int t = 0; t < mt; ++t) {
                int eA = max(min(e, cA - 1), 0);
                int eB = max(min(e, cB - 1), 0);
                int snA = csr[rA + eA];
                int snB = csr[rB + eB];
                uint2 uA = *(const uint2*)(bp + (((unsigned)snA) << 7) + fof);
                uint2 uB = *(const uint2*)(bp + (((unsigned)snB) << 7) + fof);
                bool vA = e < cA, vB = e < cB;
                float a0 = blo(uA.x), a1 = bhi(uA.x), a2 = blo(uA.y), a3 = bhi(uA.y);
                float b0 = blo(uB.x), b1 = bhi(uB.x), b2 = blo(uB.y), b3 = bhi(uB.y);
                SA0 += vA ? a0 : 0.f; SA1 += vA ? a1 : 0.f;
                SA2 += vA ? a2 : 0.f; SA3 += vA ? a3 : 0.f;
                MA0 = fmaxf(MA0, vA ? a0 : NEGINF); MA1 = fmaxf(MA1, vA ? a1 : NEGINF);
                MA2 = fmaxf(MA2, vA ? a2 : NEGINF); MA3 = fmaxf(MA3, vA ? a3 : NEGINF);
                SB0 += vB ? b0 : 0.f; SB1 += vB ? b1 : 0.f;
                SB2 += vB ? b2 : 0.f; SB3 += vB ? b3 : 0.f;
                MB0 = fmaxf(MB0, vB ? b0 : NEGINF); MB1 = fmaxf(MB1, vB ? b1 : NEGINF);
                MB2 = fmaxf(MB2, vB ? b2 : NEGINF); MB3 = fmaxf(MB3, vB ? b3 : NEGINF);
                e += 4;
            }

            #pragma unroll
            for (int m = 0; m < 2; ++m) {
                if (m == 1 && !hasB) break;
                int n = (m == 0) ? nA : nB;
                int cnt = (m == 0) ? cA : cB;
                float T0 = (m == 0) ? SA0 : SB0, T1 = (m == 0) ? SA1 : SB1;
                float T2 = (m == 0) ? SA2 : SB2, T3 = (m == 0) ? SA3 : SB3;
                float X0 = (m == 0) ? MA0 : MB0, X1 = (m == 0) ? MA1 : MB1;
                float X2 = (m == 0) ? MA2 : MB2, X3 = (m == 0) ? MA3 : MB3;
                T0 += __shfl_xor(T0, 16, 64); T1 += __shfl_xor(T1, 16, 64);
                T2 += __shfl_xor(T2, 16, 64); T3 += __shfl_xor(T3, 16, 64);
                T0 += __shfl_xor(T0, 32, 64); T1 += __shfl_xor(T1, 32, 64);
                T2 += __shfl_xor(T2, 32, 64); T3 += __shfl_xor(T3, 32, 64);
                X0 = fmaxf(X0, __shfl_xor(X0, 16, 64)); X1 = fmaxf(X1, __shfl_xor(X1, 16, 64));
                X2 = fmaxf(X2, __shfl_xor(X2, 16, 64)); X3 = fmaxf(X3, __shfl_xor(X3, 16, 64));
                X0 = fmaxf(X0, __shfl_xor(X0, 32, 64)); X1 = fmaxf(X1, __shfl_xor(X1, 32, 64));
                X2 = fmaxf(X2, __shfl_xor(X2, 32, 64)); X3 = fmaxf(X3, __shfl_xor(X3, 32, 64));
                uint2 su = *(const uint2*)(bp + (((unsigned)n) << 7) + fof);
                float w0 = blo(su.x), w1 = bhi(su.x), w2 = blo(su.y), w3 = bhi(su.y);
                T0 += w0; T1 += w1; T2 += w2; T3 += w3;
                X0 = fmaxf(X0, w0); X1 = fmaxf(X1, w1);
                X2 = fmaxf(X2, w2); X3 = fmaxf(X3, w3);
                float invd = 1.f / (float)(cnt + 1);
                float A0 = T0 * invd, A1 = T1 * invd, A2 = T2 * invd, A3 = T3 * invd;

                const unsigned short* cr = combB16 + (size_t)n * 96;
                const uint2* c0p = (const uint2*)(cr + sub * 12);
                const uint2* c1p = (const uint2*)(cr + 48 + sub * 12);
                uint2 qa0 = c0p[0], qa1 = c0p[1], qa2 = c0p[2];
                uint2 qb0 = c1p[0], qb1 = c1p[1], qb2 = c1p[2];

                float o0 = cb0, o1 = cb1;
                o0 = fmaf(blo(qa0.x), T0, o0); o0 = fmaf(bhi(qa0.x), T1, o0);
                o0 = fmaf(blo(qa0.y), T2, o0); o0 = fmaf(bhi(qa0.y), T3, o0);
                o0 = fmaf(blo(qa1.x), A0, o0); o0 = fmaf(bhi(qa1.x), A1, o0);
                o0 = fmaf(blo(qa1.y), A2, o0); o0 = fmaf(bhi(qa1.y), A3, o0);
                o0 = fmaf(blo(qa2.x), X0, o0); o0 = fmaf(bhi(qa2.x), X1, o0);
                o0 = fmaf(blo(qa2.y), X2, o0); o0 = fmaf(bhi(qa2.y), X3, o0);
                o1 = fmaf(blo(qb0.x), T0, o1); o1 = fmaf(bhi(qb0.x), T1, o1);
                o1 = fmaf(blo(qb0.y), T2, o1); o1 = fmaf(bhi(qb0.y), T3, o1);
                o1 = fmaf(blo(qb1.x), A0, o1); o1 = fmaf(bhi(qb1.x), A1, o1);
                o1 = fmaf(blo(qb1.y), A2, o1); o1 = fmaf(bhi(qb1.y), A3, o1);
                o1 = fmaf(blo(qb2.x), X0, o1); o1 = fmaf(bhi(qb2.x), X1, o1);
                o1 = fmaf(blo(qb2.y), X2, o1); o1 = fmaf(bhi(qb2.y), X3, o1);

                outb[(size_t)n * 128 + l] = f2bf(o0);
                outb[(size_t)n * 128 + 64 + l] = f2bf(o1);
                s0 += o0; q0 += o0 * o0; s1 += o1; q1 += o1 * o1;
            }
        }
    }
    __shared__ float sred[4][256];
    sred[0][threadIdx.x] = s0; sred[1][threadIdx.x] = q0;
    sred[2][threadIdx.x] = s1; sred[3][threadIdx.x] = q1;
    __syncthreads();
    if (threadIdx.x < 64) {
        int t = threadIdx.x;
        float v0 = sred[0][t] + sred[0][t + 64] + sred[0][t + 128] + sred[0][t + 192];
        float v1 = sred[1][t] + sred[1][t + 64] + sred[1][t + 128] + sred[1][t + 192];
        float v2 = sred[2][t] + sred[2][t + 64] + sred[2][t + 128] + sred[2][t + 192];
        float v3 = sred[3][t] + sred[3][t + 64] + sred[3][t + 128] + sred[3][t + 192];
        atomicAdd(stats + t, v0);
        atomicAdd(stats + 128 + t, v1);
        atomicAdd(stats + 64 + t, v2);
        atomicAdd(stats + 192 + t, v3);
    }
}

// ---------------------------------------------------------------- pool (final BN + mean) fused with mlp1
__global__ __launch_bounds__(256)
void k_pool(const unsigned short* __restrict__ t, const unsigned short* __restrict__ h,
            const float* __restrict__ stats, const float* __restrict__ gamma,
            const float* __restrict__ beta, float invN, const int* __restrict__ gstart,
            const float* __restrict__ w1, float* __restrict__ t1,
            float* __restrict__ st5, int G)
{
    __shared__ float tg[128];
    __shared__ float part[128];
    __shared__ float red[4][64];
    int g = blockIdx.x;
    if (g >= G) return;
    int tid = threadIdx.x;
    {
        int c = tid & 127, half = tid >> 7;
        float mu  = stats[c] * invN;
        float var = stats[128 + c] * invN - mu * mu;
        float sc  = gamma[c] * rsqrtf(var + EPSV);
        float sh  = beta[c] - mu * sc;
        int s = gstart[g], e = gstart[g + 1];
        float acc = 0.f;
        #pragma unroll 2
        for (int n = s + half; n < e; n += 2) {
            size_t o = (size_t)n * 128 + c;
            acc += bfu(h[o]) + fmaxf(bfu(t[o]) * sc + sh, 0.f);
        }
        if (half) part[c] = acc;
        __syncthreads();
        if (!half) tg[c] = (acc + part[c]) / fmaxf((float)(e - s), 1.f);
        __syncthreads();
    }
    {
        int cc = tid & 63, pp = tid >> 6;
        float a = 0.f;
        int k0 = pp * 32;
        #pragma unroll
        for (int k = 0; k < 32; ++k)
            a = fmaf(tg[k0 + k], w1[(k0 + k) * 64 + cc], a);
        red[pp][cc] = a;
        __syncthreads();
        if (tid < 64) {
            float v = red[0][tid] + red[1][tid] + red[2][tid] + red[3][tid];
            t1[g * 64 + tid] = v;
            atomicAdd(st5 + tid, v);
            atomicAdd(st5 + 64 + tid, v * v);
        }
    }
}

// ---------------------------------------------------------------- MLP tail
__global__ void k_mlp2(const float* __restrict__ t1, const float* __restrict__ stats1,
                       const float* __restrict__ g1, const float* __restrict__ b1,
                       const float* __restrict__ w2, float* __restrict__ t2,
                       float* __restrict__ stats2, float invG, int G)
{
    __shared__ float row[64];
    int g = blockIdx.x;
    int c = threadIdx.x;
    float v = t1[g * 64 + c];
    float mu = stats1[c] * invG;
    float var = stats1[64 + c] * invG - mu * mu;
    row[c] = fmaxf(g1[c] * (v - mu) * rsqrtf(var + EPSV) + b1[c], 0.f);
    __syncthreads();
    if (c < 32) {
        float acc = 0.f;
        #pragma unroll
        for (int k = 0; k < 64; ++k) acc = fmaf(row[k], w2[k * 32 + c], acc);
        t2[g * 32 + c] = acc;
        atomicAdd(stats2 + c, acc);
        atomicAdd(stats2 + 32 + c, acc * acc);
    }
}

__global__ void k_mlp3(const float* __restrict__ t2, const float* __restrict__ stats2,
                       const float* __restrict__ g2, const float* __restrict__ b2,
                       const float* __restrict__ w3, const float* __restrict__ b3,
                       float* __restrict__ out, float invG, int G)
{
    __shared__ float row[32];
    int g = blockIdx.x;
    int c = threadIdx.x;
    if (c < 32) {
        float v = t2[g * 32 + c];
        float mu = stats2[c] * invG;
        float var = stats2[32 + c] * invG - mu * mu;
        row[c] = fmaxf(g2[c] * (v - mu) * rsqrtf(var + EPSV) + b2[c], 0.f);
    }
    __syncthreads();
    if (c < 10) {
        float acc = b3[c];
        #pragma unroll
        for (int k = 0; k < 32; ++k) acc = fmaf(row[k], w3[k * 10 + c], acc);
        out[g * 10 + c] = acc;
    }
}

// ---------------------------------------------------------------- launch
extern "C" void kernel_launch(void* const* d_in, const int* in_sizes, int n_in,
                              void* d_out, int out_size, void* d_ws, size_t ws_size,
                              hipStream_t stream)
{
    const float* x        = (const float*)d_in[0];
    const float* lin1_w   = (const float*)d_in[1];
    const float* lin1_b   = (const float*)d_in[2];
    const float* bn1_g    = (const float*)d_in[3];
    const float* bn1_b    = (const float*)d_in[4];
    const float* bases_w  = (const float*)d_in[5];
    const float* comb_w   = (const float*)d_in[6];
    const float* comb_b   = (const float*)d_in[7];
    const float* conv_bias= (const float*)d_in[8];
    const float* bn_g     = (const float*)d_in[9];
    const float* bn_b     = (const float*)d_in[10];
    const float* mlp_w1   = (const float*)d_in[11];
    const float* mbn1_g   = (const float*)d_in[12];
    const float* mbn1_b   = (const float*)d_in[13];
    const float* mlp_w2   = (const float*)d_in[14];
    const float* mbn2_g   = (const float*)d_in[15];
    const float* mbn2_b   = (const float*)d_in[16];
    const float* mlp_w3   = (const float*)d_in[17];
    const float* mlp_b3   = (const float*)d_in[18];
    const int*   edge_idx = (const int*)d_in[19];
    const int*   batch    = (const int*)d_in[20];
    float* outp = (float*)d_out;

    const int N = in_sizes[20];
    const int E = in_sizes[19] / 2;
    const int G = out_size / 10;
    const int* esrc = edge_idx;
    const int* edst = edge_idx + E;

    int shift = 6;
    while ((((N - 1) >> shift) + 1) > NBMAX && shift < 7) ++shift;
    const int NB = ((N - 1) >> shift) + 1;

    char* p = (char*)d_ws;
    auto alloc = [&](size_t bytes) {
        char* r = p;
        p += (bytes + 255) & ~(size_t)255;
        return r;
    };
    unsigned short* h      = (unsigned short*)alloc((size_t)N * 128 * 2);
    unsigned short* basesP = (unsigned short*)alloc((size_t)N * 64 * 2);
    unsigned short* combB16= (unsigned short*)alloc((size_t)N * 96 * 2);
    unsigned short* outb   = (unsigned short*)alloc((size_t)N * 128 * 2);
    int*            csr    = (int*)  alloc((size_t)(E + 64) * 4);
    int*            rowptr = (int*)  alloc((size_t)(N + 1) * 4);
    int*            bbase  = (int*)  alloc((size_t)(NB + 1) * 4);
    float*          t1     = (float*)alloc((size_t)G * 64 * 4);
    float*          t2     = (float*)alloc((size_t)G * 32 * 4);
    int*            gstart = (int*)  alloc((size_t)(G + 1) * 4);
    char*           zbase  = p;
    int*            bcnt   = (int*)  alloc((size_t)NB * 4);
    int*            bcur0  = (int*)  alloc((size_t)NB * 4);
    float*          stats  = (float*)alloc(7 * 256 * 4);
    int*            arrive = (int*)  alloc(2 * 4);
    size_t zbytes = (size_t)(p - zbase);
    uint2* bucketed = (uint2*)combB16;   // alias: CSR build done before gemm writes
    (void)ws_size; (void)n_in;

    hipMemsetAsync(zbase, 0, zbytes, stream);

    const float invN = 1.0f / (float)N;
    const float invG = 1.0f / (float)G;

    k_lin1<<<1024, 256, 0, stream>>>(x, lin1_w, lin1_b, outb, stats, N);
    k_prep<<<768, 256, 0, stream>>>(edst, bcnt, bbase, E, NB, shift,
                                    batch, gstart, N, G, arrive);
    k_p2_scatter<<<(E + CHUNK - 1) / CHUNK, 256, 0, stream>>>(esrc, edst, bbase, bcur0,
                                                              bucketed, E, NB, shift);
    k_p3_csr<<<NB, 256, 0, stream>>>(bucketed, bbase, rowptr, csr, N, NB, shift);

    for (int l = 0; l < 4; ++l) {
        const float* bw = bases_w + (size_t)l * 128 * 64;
        const float* cw = comb_w + (size_t)l * 128 * 96;
        const float* cb = comb_b + (size_t)l * 96;
        const float* cvb = conv_bias + (size_t)l * 128;
        const float* pg = (l == 0) ? bn1_g : bn_g + (l - 1) * 128;
        const float* pb = (l == 0) ? bn1_b : bn_b + (l - 1) * 128;
        k_gemm_mfma<<<512, 256, 0, stream>>>(outb, h, stats + l * 256, pg, pb, invN,
                                             l > 0 ? 1 : 0, bw, cw, cb, basesP, combB16, N);
        k_agg<<<2048, 256, 0, stream>>>(basesP, combB16, csr, rowptr, cvb,
                                        outb, stats + (1 + l) * 256, N);
    }

    k_pool<<<G, 256, 0, stream>>>(outb, h, stats + 4 * 256, bn_g + 3 * 128,
                                  bn_b + 3 * 128, invN, gstart,
                                  mlp_w1, t1, stats + 5 * 256, G);
    float* st5 = stats + 5 * 256;
    float* st6 = stats + 6 * 256;
    k_mlp2<<<G, 64, 0, stream>>>(t1, st5, mbn1_g, mbn1_b, mlp_w2, t2, st6, invG, G);
    k_mlp3<<<G, 64, 0, stream>>>(t2, st6, mbn2_g, mbn2_b, mlp_w3, mlp_b3, outp, invG, G);
}